// Round 11
// baseline (298.205 us; speedup 1.0000x reference)
//
#include <hip/hip_runtime.h>
#include <hip/hip_bf16.h>
#include <stdint.h>

#define D_MODEL 1024
#define NHEAD 16
#define DKH 64
#define BATCH 2
#define SEQ 2048
#define LOG2E 1.44269504088896f

typedef __bf16 bf16_t;
typedef __bf16 bf16x8 __attribute__((ext_vector_type(8)));
typedef float f32x4 __attribute__((ext_vector_type(4)));
typedef float f32x16 __attribute__((ext_vector_type(16)));

__device__ __forceinline__ float fast_exp2(float x) {
#if __has_builtin(__builtin_amdgcn_exp2f)
  return __builtin_amdgcn_exp2f(x);
#else
  return exp2f(x);
#endif
}

// ---------- async global->LDS (16B per lane) ----------
__device__ __forceinline__ void gload_lds16(const bf16_t* g, bf16_t* l) {
  auto gp = (const __attribute__((address_space(1))) void*)(uintptr_t)g;
  auto lp = (__attribute__((address_space(3))) void*)(uintptr_t)l;
  __builtin_amdgcn_global_load_lds(gp, lp, 16, 0, 0);
}

// pack two f32 -> u32 of 2 bf16 (compiler emits v_cvt_pk_bf16_f32)
__device__ __forceinline__ uint32_t pkbf(float lo, float hi) {
  bf16_t a = (bf16_t)lo, c = (bf16_t)hi;
  uint16_t ua, uc;
  __builtin_memcpy(&ua, &a, 2);
  __builtin_memcpy(&uc, &c, 2);
  return (uint32_t)ua | ((uint32_t)uc << 16);
}

// v_permlane32_swap_b32 a, b: swaps a.lanes[32:63] <-> b.lanes[0:31]
// Call as perm32swap(low_kv_word, high_kv_word). (validated R7)
__device__ __forceinline__ void perm32swap(uint32_t& a, uint32_t& b) {
  asm volatile("v_permlane32_swap_b32 %0, %1" : "+v"(a), "+v"(b));
}

// Fused weight conversion.  n<3072: WqkvT[n][d] (Q scaled by 0.125*log2e);
// n>=3072: WoT[n-3072][d] = WO[d][n-3072].
__global__ void k_cvtw(const float* __restrict__ WQ, const float* __restrict__ WK,
                       const float* __restrict__ WV, const float* __restrict__ WO,
                       bf16_t* __restrict__ wt) {
  int j = blockIdx.x * 256 + threadIdx.x;        // 4M outputs
  int d = j & 1023, n = j >> 10;
  if (n < 3072) {
    int proj = n >> 10, h = (n >> 6) & 15, k = n & 63;
    const float* w = proj == 0 ? WQ : (proj == 1 ? WK : WV);
    float scale = proj == 0 ? (0.125f * LOG2E) : 1.0f;
    wt[j] = (bf16_t)(w[(h << 16) + (d << 6) + k] * scale);
  } else {
    wt[j] = (bf16_t)WO[(d << 10) + (n - 3072)];
  }
}

// Mask pre-gather for 32x32 swapped-QK D-layout, scaled by log2e. (validated R7)
__global__ void k_maskg(const float* __restrict__ M, bf16_t* __restrict__ Mf) {
  int t = blockIdx.x * 256 + threadIdx.x;        // 1M threads, 4 vals each
  int wch = t & 7, lane = (t >> 3) & 63;
  int kvt = (t >> 9) & 31, qt = t >> 14;
  int h = lane >> 5, ql = lane & 31;
  int q = qt * 32 + ql;
  int t32 = wch >> 2, r2 = wch & 3;
  int kvb = kvt * 64 + t32 * 32 + 8 * r2 + 4 * h;
  float4 m4 = *reinterpret_cast<const float4*>(M + (size_t)q * SEQ + kvb);
  bf16_t o[4];
  o[0] = (bf16_t)(m4.x * LOG2E); o[1] = (bf16_t)(m4.y * LOG2E);
  o[2] = (bf16_t)(m4.z * LOG2E); o[3] = (bf16_t)(m4.w * LOG2E);
  *reinterpret_cast<ushort4*>(Mf + (size_t)t * 4) = *reinterpret_cast<ushort4*>(o);
}

// ---------- fused QKV projection GEMM, f32 A inputs converted in-staging ----------
__global__ __launch_bounds__(256)
void k_gemm_qkv(const float* __restrict__ Qs, const float* __restrict__ Ks32,
                const float* __restrict__ Vs32, const bf16_t* __restrict__ Bt,
                bf16_t* __restrict__ qh, bf16_t* __restrict__ Kf,
                bf16_t* __restrict__ Vf) {
  __shared__ __align__(16) bf16_t As[128 * 32];
  __shared__ __align__(16) bf16_t Bs[128 * 32];
  const int tid = threadIdx.x;
  const int lane = tid & 63, wave = tid >> 6;
  const int g = lane >> 4, lr = lane & 15;
  const int bm = blockIdx.x, bn = blockIdx.y;
  const int pn = bn >> 3;   // 0:q 1:k 2:v  (block-uniform)
  const float* Ap32 = pn == 0 ? Qs : (pn == 1 ? Ks32 : Vs32);
  const int wm = (wave >> 1) << 6, wn = (wave & 1) << 6;
  const int arow = tid >> 1, ako = (tid & 1) << 4;
  const float* aptr = Ap32 + (size_t)(bm * 128 + arow) * 1024 + ako;
  f32x4 acc[4][4] = {};

  float4 fA0 = *reinterpret_cast<const float4*>(aptr);
  float4 fA1 = *reinterpret_cast<const float4*>(aptr + 4);
  float4 fA2 = *reinterpret_cast<const float4*>(aptr + 8);
  float4 fA3 = *reinterpret_cast<const float4*>(aptr + 12);

  for (int kt = 0; kt < 1024; kt += 32) {
#pragma unroll
    for (int cc = 0; cc < 2; cc++) {
      int c = tid + cc * 256;
      int row = c >> 2, ko = (c & 3) << 3;
      gload_lds16(Bt + (size_t)(bn * 128 + row) * 1024 + kt + ko, Bs + c * 8);
    }
    {
      bf16x8 o0, o1;
      o0[0] = (bf16_t)fA0.x; o0[1] = (bf16_t)fA0.y; o0[2] = (bf16_t)fA0.z; o0[3] = (bf16_t)fA0.w;
      o0[4] = (bf16_t)fA1.x; o0[5] = (bf16_t)fA1.y; o0[6] = (bf16_t)fA1.z; o0[7] = (bf16_t)fA1.w;
      o1[0] = (bf16_t)fA2.x; o1[1] = (bf16_t)fA2.y; o1[2] = (bf16_t)fA2.z; o1[3] = (bf16_t)fA2.w;
      o1[4] = (bf16_t)fA3.x; o1[5] = (bf16_t)fA3.y; o1[6] = (bf16_t)fA3.z; o1[7] = (bf16_t)fA3.w;
      *reinterpret_cast<bf16x8*>(As + arow * 32 + ako) = o0;
      *reinterpret_cast<bf16x8*>(As + arow * 32 + ako + 8) = o1;
    }
    if (kt + 32 < 1024) {
      const float* np = aptr + kt + 32;
      fA0 = *reinterpret_cast<const float4*>(np);
      fA1 = *reinterpret_cast<const float4*>(np + 4);
      fA2 = *reinterpret_cast<const float4*>(np + 8);
      fA3 = *reinterpret_cast<const float4*>(np + 12);
    }
    __syncthreads();
    bf16x8 af[4], bfr[4];
#pragma unroll
    for (int t = 0; t < 4; t++)
      af[t] = *reinterpret_cast<const bf16x8*>(As + (wm + t * 16 + lr) * 32 + g * 8);
#pragma unroll
    for (int t = 0; t < 4; t++)
      bfr[t] = *reinterpret_cast<const bf16x8*>(Bs + (wn + t * 16 + lr) * 32 + g * 8);
    __builtin_amdgcn_s_setprio(1);
#pragma unroll
    for (int i = 0; i < 4; i++)
#pragma unroll
      for (int j = 0; j < 4; j++)
        acc[i][j] = __builtin_amdgcn_mfma_f32_16x16x32_bf16(af[i], bfr[j], acc[i][j], 0, 0, 0);
    __builtin_amdgcn_s_setprio(0);
    __syncthreads();
  }

#pragma unroll
  for (int i = 0; i < 4; i++)
#pragma unroll
    for (int j = 0; j < 4; j++)
#pragma unroll
      for (int e = 0; e < 4; e++) {
        int row = (bm << 7) + wm + i * 16 + g * 4 + e;       // b*SEQ + s
        int col = ((bn & 7) << 7) + wn + j * 16 + lr;        // h*64 + d
        float v = acc[i][j][e];
        int b = row >> 11, s = row & 2047, h = col >> 6, d = col & 63;
        size_t bh32 = (size_t)((b << 4) + h) * 32;
        if (pn == 0) {
          qh[((size_t)(((b << 4) + h) * SEQ + s) << 6) + d] = (bf16_t)v;
        } else if (pn == 1) {
          int kt2 = s >> 6, u = s & 63, t32 = u >> 5, ql2 = u & 31;
          int kk2 = d >> 4, hq2 = (d >> 3) & 1, e2 = d & 7;
          Kf[(bh32 + kt2) * 4096 + (t32 * 4 + kk2) * 512 + (hq2 * 32 + ql2) * 8 + e2] = (bf16_t)v;
        } else {
          int kt2 = s >> 6, u = s & 63, s2 = u >> 4, hq2 = (u >> 3) & 1, e2 = u & 7;
          int dkt = d >> 5, ql2 = d & 31;
          Vf[(bh32 + kt2) * 4096 + (dkt * 4 + s2) * 512 + (hq2 * 32 + ql2) * 8 + e2] = (bf16_t)v;
        }
      }
}

// ---------- WO GEMM: [4096x1024] x [1024x1024]^T -> fp32, 64x128 tiles ----------
__global__ __launch_bounds__(256)
void k_gemm_wo(const bf16_t* __restrict__ A, const bf16_t* __restrict__ Bt,
               float* __restrict__ C) {
  __shared__ __align__(16) bf16_t As[64 * 32];
  __shared__ __align__(16) bf16_t Bs[128 * 32];
  const int tid = threadIdx.x;
  const int lane = tid & 63, wave = tid >> 6;
  const int g = lane >> 4, lr = lane & 15;
  const int bm = blockIdx.x, bn = blockIdx.y;
  const int wm = (wave >> 1) << 5, wn = (wave & 1) << 6;
  f32x4 acc[2][4] = {};

  for (int kt = 0; kt < 1024; kt += 32) {
    {
      int row = tid >> 2, ko = (tid & 3) << 3;
      gload_lds16(A + (size_t)(bm * 64 + row) * 1024 + kt + ko, As + tid * 8);
    }
#pragma unroll
    for (int cc = 0; cc < 2; cc++) {
      int c = tid + cc * 256;
      int row = c >> 2, ko = (c & 3) << 3;
      gload_lds16(Bt + (size_t)(bn * 128 + row) * 1024 + kt + ko, Bs + c * 8);
    }
    __syncthreads();
    bf16x8 af[2], bfr[4];
#pragma unroll
    for (int t = 0; t < 2; t++)
      af[t] = *reinterpret_cast<const bf16x8*>(As + (wm + t * 16 + lr) * 32 + g * 8);
#pragma unroll
    for (int t = 0; t < 4; t++)
      bfr[t] = *reinterpret_cast<const bf16x8*>(Bs + (wn + t * 16 + lr) * 32 + g * 8);
    __builtin_amdgcn_s_setprio(1);
#pragma unroll
    for (int i = 0; i < 2; i++)
#pragma unroll
      for (int j = 0; j < 4; j++)
        acc[i][j] = __builtin_amdgcn_mfma_f32_16x16x32_bf16(af[i], bfr[j], acc[i][j], 0, 0, 0);
    __builtin_amdgcn_s_setprio(0);
    __syncthreads();
  }
#pragma unroll
  for (int i = 0; i < 2; i++)
#pragma unroll
    for (int j = 0; j < 4; j++)
#pragma unroll
      for (int e = 0; e < 4; e++) {
        int row = (bm << 6) + wm + i * 16 + g * 4 + e;
        int col = (bn << 7) + wn + j * 16 + lr;
        C[(size_t)row * D_MODEL + col] = acc[i][j][e];
      }
}

// ---------- flash attention v9: K in LDS, V direct from L2, 36KB LDS ----------
// 1D grid 512 blocks, 512 thr = 8 waves: wave w = (kvhalf hh = w>>2)*4 + qw.
// bid&7 = XCD cluster (validated R10).  V hot set 1MB/XCD -> L2-resident, so
// V skips LDS entirely (guide CM#7); LDS 64->36KB raises blocks/CU 2->3-4.
__global__ __launch_bounds__(512, 6)
void k_attn7(const bf16_t* __restrict__ Qh, const bf16_t* __restrict__ Kf,
             const bf16_t* __restrict__ Vf, const bf16_t* __restrict__ Mf,
             bf16_t* __restrict__ O) {
  __shared__ __align__(16) char smem[36864];   // Ks[2][2][4096]b16 (32KB) U merge(36KB)
  bf16_t* KsB = reinterpret_cast<bf16_t*>(smem);
  const int bid = blockIdx.x;
  const int xcd = bid & 7, loc = bid >> 3;
  const int bh = xcd * 4 + (loc >> 4);      // 4 bh per XCD
  const int qtile = loc & 15;
  const int b = bh >> 4, h = bh & 15;
  const int tid = threadIdx.x, w = tid >> 6, lane = tid & 63;
  const int qw = w & 3, hh = w >> 2;
  const int hq = lane >> 5, ql = lane & 31;
  const int tid256 = tid & 255;
  const int qbase = qtile * 128 + qw * 32;
  const bf16_t* qp = Qh + (size_t)bh * SEQ * DKH;
  const bf16_t* kfp = Kf + (size_t)bh * 32 * 4096;
  const bf16_t* vfp = Vf + (size_t)bh * 32 * 4096;
  const int qt = qtile * 4 + qw;
  const bf16_t* mp = Mf + ((size_t)(qt * 32 + hh * 16) * 64 + lane) * 32;
  const int NIT = 16;

  bf16x8 aq[4];
#pragma unroll
  for (int kk = 0; kk < 4; kk++)
    aq[kk] = *reinterpret_cast<const bf16x8*>(
        qp + (size_t)(qbase + ql) * DKH + kk * 16 + hq * 8);

  f32x16 oacc[2] = {};
  float lsum = 0.f;

  auto stage = [&](int buf, int kt) {
#pragma unroll
    for (int cc = 0; cc < 2; cc++) {
      int c = tid256 + cc * 256;        // 512 16B-units of K tile, fully linear
      gload_lds16(kfp + (size_t)kt * 4096 + c * 8,
                  KsB + (hh * 2 + buf) * 4096 + c * 8);
    }
  };

  stage(0, hh * 16);
  bf16x8 mv[4];
#pragma unroll
  for (int j = 0; j < 4; j++)
    mv[j] = *reinterpret_cast<const bf16x8*>(mp + j * 8);
  __syncthreads();

  for (int it = 0; it < NIT; ++it) {
    const int cur = it & 1;
    if (it + 1 < NIT) stage(cur ^ 1, hh * 16 + it + 1);

    const bf16_t* kb = KsB + (hh * 2 + cur) * 4096;
    const bf16_t* vt = vfp + (size_t)(hh * 16 + it) * 4096 + lane * 8;

    // S^T = K Q^T : D[kv 32 rows][q = ql], rows = (reg&3)+8*(reg>>2)+4*hq
    f32x16 p[2];
#pragma unroll
    for (int t32 = 0; t32 < 2; t32++) {
      f32x16 a = {};
      __builtin_amdgcn_s_setprio(1);
#pragma unroll
      for (int kk = 0; kk < 4; kk++) {
        bf16x8 bk = *reinterpret_cast<const bf16x8*>(kb + (t32 * 4 + kk) * 512 + lane * 8);
        a = __builtin_amdgcn_mfma_f32_32x32x16_bf16(bk, aq[kk], a, 0, 0, 0);
      }
      __builtin_amdgcn_s_setprio(0);
      p[t32] = a;
    }

    // mask + exp2 -> pack to PV A-frags via permlane32_swap (validated R7)
    bf16x8 paf[4];
#pragma unroll
    for (int s = 0; s < 4; s++) {
      const int t32 = s >> 1, rb = (s & 1) * 8;
      float pes[8];
#pragma unroll
      for (int j = 0; j < 8; j++) {
        int v = t32 * 16 + rb + j;
        float x = p[t32][rb + j] + (float)mv[v >> 3][v & 7];
        float pe = fast_exp2(x);
        lsum += pe;
        pes[j] = pe;
      }
      uint32_t u0 = pkbf(pes[0], pes[1]), u1 = pkbf(pes[2], pes[3]);
      uint32_t w0 = pkbf(pes[4], pes[5]), w1 = pkbf(pes[6], pes[7]);
      perm32swap(u0, w0);          // low-kv word FIRST (vdst), high second
      perm32swap(u1, w1);
      union { uint32_t wd[4]; bf16x8 v8; } fu;
      fu.wd[0] = u0; fu.wd[1] = u1; fu.wd[2] = w0; fu.wd[3] = w1;
      paf[s] = fu.v8;
    }

    // prefetch next iter's mask (consumed after the barrier)
    {
      const bf16_t* mn = mp + (size_t)((it + 1 < NIT) ? (it + 1) : it) * 2048;
#pragma unroll
      for (int j = 0; j < 4; j++)
        mv[j] = *reinterpret_cast<const bf16x8*>(mn + j * 8);
    }

    // O += P V : A = paf, B = V frag loaded straight from L2 (linear, imm offsets)
#pragma unroll
    for (int dkt = 0; dkt < 2; dkt++) {
      bf16x8 bv[4];
#pragma unroll
      for (int s = 0; s < 4; s++)
        bv[s] = *reinterpret_cast<const bf16x8*>(vt + (dkt * 4 + s) * 512);
      __builtin_amdgcn_s_setprio(1);
#pragma unroll
      for (int s = 0; s < 4; s++)
        oacc[dkt] = __builtin_amdgcn_mfma_f32_32x32x16_bf16(paf[s], bv[s], oacc[dkt], 0, 0, 0);
      __builtin_amdgcn_s_setprio(0);
    }
    __syncthreads();
  }

  // merge kv-halves via LDS union (smO 32KB + smL 4KB), normalize + write (validated R8)
  float* smO = (float*)smem;
  float* smL = (float*)(smem + 32768);
  if (w >= 4) {
    int base = (qw * 64 + lane) * 32;
#pragma unroll
    for (int dkt = 0; dkt < 2; dkt++)
#pragma unroll
      for (int cg = 0; cg < 4; cg++) {
        int chs = ((dkt * 4 + cg) ^ (lane & 7)) * 4;
        float4 val = {oacc[dkt][cg * 4], oacc[dkt][cg * 4 + 1],
                      oacc[dkt][cg * 4 + 2], oacc[dkt][cg * 4 + 3]};
        *reinterpret_cast<float4*>(&smO[base + chs]) = val;
      }
    smL[qw * 64 + lane] = lsum;
  }
  __syncthreads();
  if (w < 4) {
    int base = (qw * 64 + lane) * 32;
#pragma unroll
    for (int dkt = 0; dkt < 2; dkt++)
#pragma unroll
      for (int cg = 0; cg < 4; cg++) {
        int chs = ((dkt * 4 + cg) ^ (lane & 7)) * 4;
        float4 pv = *reinterpret_cast<const float4*>(&smO[base + chs]);
#pragma unroll
        for (int e = 0; e < 4; e++) oacc[dkt][cg * 4 + e] += pv[e];
      }
    lsum += smL[qw * 64 + lane];
    float lf = lsum + __shfl_xor(lsum, 32);   // full row-sum for q = qbase+ql
    float inv[16];
#pragma unroll
    for (int reg = 0; reg < 16; reg++) {
      int qrow = (reg & 3) + 8 * (reg >> 2) + 4 * hq;
      inv[reg] = 1.0f / __shfl(lf, qrow);
    }
#pragma unroll
    for (int dkt = 0; dkt < 2; dkt++)
#pragma unroll
      for (int reg = 0; reg < 16; reg++) {
        int qrow = (reg & 3) + 8 * (reg >> 2) + 4 * hq;
        float v = oacc[dkt][reg] * inv[reg];
        O[(size_t)(b * SEQ + qbase + qrow) * D_MODEL + (h << 6) + dkt * 32 + ql] = (bf16_t)v;
      }
  }
}

extern "C" void kernel_launch(void* const* d_in, const int* in_sizes, int n_in,
                              void* d_out, int out_size, void* d_ws, size_t ws_size,
                              hipStream_t stream) {
  const float* Q  = (const float*)d_in[0];
  const float* K  = (const float*)d_in[1];
  const float* V  = (const float*)d_in[2];
  const float* M  = (const float*)d_in[3];
  const float* WQ = (const float*)d_in[5];
  const float* WK = (const float*)d_in[6];
  const float* WV = (const float*)d_in[7];
  const float* WO = (const float*)d_in[8];

  char* ws = (char*)d_ws;
  const size_t MB = 1 << 20;
  bf16_t* Mf    = (bf16_t*)(ws + 24 * MB);   // 8 MB fragment-order mask
  bf16_t* WqkvT = (bf16_t*)(ws + 32 * MB);   // 6 MB [3072][1024]
  bf16_t* WoT   = (bf16_t*)(ws + 38 * MB);   // 2 MB (contiguous after WqkvT)
  bf16_t* qh    = (bf16_t*)(ws + 40 * MB);   // [B,H,S,dk]
  bf16_t* Kf    = (bf16_t*)(ws + 48 * MB);   // 8 MB K fragment-order
  bf16_t* Vf    = (bf16_t*)(ws + 56 * MB);   // 8 MB V fragment-order
  bf16_t* Ob    = (bf16_t*)(ws + 64 * MB);   // [B,S,H*dk]

  k_maskg<<<4096, 256, 0, stream>>>(M, Mf);
  k_cvtw<<<16384, 256, 0, stream>>>(WQ, WK, WV, WO, WqkvT);

  k_gemm_qkv<<<dim3(32, 24), 256, 0, stream>>>(Q, K, V, WqkvT, qh, Kf, Vf);

  k_attn7<<<512, 512, 0, stream>>>(qh, Kf, Vf, Mf, Ob);

  k_gemm_wo<<<dim3(64, 8), 256, 0, stream>>>(Ob, WoT, (float*)d_out);
}

// Round 12
// 176.473 us; speedup vs baseline: 1.6898x; 1.6898x over previous
//
#include <hip/hip_runtime.h>
#include <hip/hip_bf16.h>
#include <stdint.h>

#define D_MODEL 1024
#define NHEAD 16
#define DKH 64
#define BATCH 2
#define SEQ 2048
#define LOG2E 1.44269504088896f

typedef __bf16 bf16_t;
typedef __bf16 bf16x8 __attribute__((ext_vector_type(8)));
typedef float f32x4 __attribute__((ext_vector_type(4)));
typedef float f32x16 __attribute__((ext_vector_type(16)));

__device__ __forceinline__ float fast_exp2(float x) {
#if __has_builtin(__builtin_amdgcn_exp2f)
  return __builtin_amdgcn_exp2f(x);
#else
  return exp2f(x);
#endif
}

// ---------- async global->LDS (16B per lane) ----------
__device__ __forceinline__ void gload_lds16(const bf16_t* g, bf16_t* l) {
  auto gp = (const __attribute__((address_space(1))) void*)(uintptr_t)g;
  auto lp = (__attribute__((address_space(3))) void*)(uintptr_t)l;
  __builtin_amdgcn_global_load_lds(gp, lp, 16, 0, 0);
}

// pack two f32 -> u32 of 2 bf16 (compiler emits v_cvt_pk_bf16_f32)
__device__ __forceinline__ uint32_t pkbf(float lo, float hi) {
  bf16_t a = (bf16_t)lo, c = (bf16_t)hi;
  uint16_t ua, uc;
  __builtin_memcpy(&ua, &a, 2);
  __builtin_memcpy(&uc, &c, 2);
  return (uint32_t)ua | ((uint32_t)uc << 16);
}

// v_permlane32_swap_b32 a, b: swaps a.lanes[32:63] <-> b.lanes[0:31]
// Call as perm32swap(low_kv_word, high_kv_word). (validated R7)
__device__ __forceinline__ void perm32swap(uint32_t& a, uint32_t& b) {
  asm volatile("v_permlane32_swap_b32 %0, %1" : "+v"(a), "+v"(b));
}

// load 16 consecutive f32 (compiler emits 4x global_load_dwordx4)
__device__ __forceinline__ f32x16 ld16f(const float* p) {
  union { float4 q[4]; f32x16 v; } u;
  u.q[0] = *reinterpret_cast<const float4*>(p);
  u.q[1] = *reinterpret_cast<const float4*>(p + 4);
  u.q[2] = *reinterpret_cast<const float4*>(p + 8);
  u.q[3] = *reinterpret_cast<const float4*>(p + 12);
  return u.v;
}

// Fused weight conversion.  n<3072: WqkvT[n][d] (Q scaled by 0.125*log2e);
// n>=3072: WoT[n-3072][d] = WO[d][n-3072].
__global__ void k_cvtw(const float* __restrict__ WQ, const float* __restrict__ WK,
                       const float* __restrict__ WV, const float* __restrict__ WO,
                       bf16_t* __restrict__ wt) {
  int j = blockIdx.x * 256 + threadIdx.x;        // 4M outputs
  int d = j & 1023, n = j >> 10;
  if (n < 3072) {
    int proj = n >> 10, h = (n >> 6) & 15, k = n & 63;
    const float* w = proj == 0 ? WQ : (proj == 1 ? WK : WV);
    float scale = proj == 0 ? (0.125f * LOG2E) : 1.0f;
    wt[j] = (bf16_t)(w[(h << 16) + (d << 6) + k] * scale);
  } else {
    wt[j] = (bf16_t)WO[(d << 10) + (n - 3072)];
  }
}

// Mask pre-gather for 32x32 swapped-QK D-layout, scaled by log2e, F32 OUTPUT
// (consumed directly as the QK^T MFMA C-operand).  Same index algebra as the
// R7-validated bf16 version.
__global__ void k_maskg(const float* __restrict__ M, float* __restrict__ Mf) {
  int t = blockIdx.x * 256 + threadIdx.x;        // 1M threads, 4 vals each
  int wch = t & 7, lane = (t >> 3) & 63;
  int kvt = (t >> 9) & 31, qt = t >> 14;
  int h = lane >> 5, ql = lane & 31;
  int q = qt * 32 + ql;
  int t32 = wch >> 2, r2 = wch & 3;
  int kvb = kvt * 64 + t32 * 32 + 8 * r2 + 4 * h;
  float4 m4 = *reinterpret_cast<const float4*>(M + (size_t)q * SEQ + kvb);
  float4 o = {m4.x * LOG2E, m4.y * LOG2E, m4.z * LOG2E, m4.w * LOG2E};
  *reinterpret_cast<float4*>(Mf + (size_t)t * 4) = o;
}

// ---------- fused QKV projection GEMM, f32 A inputs converted in-staging ----------
__global__ __launch_bounds__(256)
void k_gemm_qkv(const float* __restrict__ Qs, const float* __restrict__ Ks32,
                const float* __restrict__ Vs32, const bf16_t* __restrict__ Bt,
                bf16_t* __restrict__ qh, bf16_t* __restrict__ Kf,
                bf16_t* __restrict__ Vf) {
  __shared__ __align__(16) bf16_t As[128 * 32];
  __shared__ __align__(16) bf16_t Bs[128 * 32];
  const int tid = threadIdx.x;
  const int lane = tid & 63, wave = tid >> 6;
  const int g = lane >> 4, lr = lane & 15;
  const int bm = blockIdx.x, bn = blockIdx.y;
  const int pn = bn >> 3;   // 0:q 1:k 2:v  (block-uniform)
  const float* Ap32 = pn == 0 ? Qs : (pn == 1 ? Ks32 : Vs32);
  const int wm = (wave >> 1) << 6, wn = (wave & 1) << 6;
  const int arow = tid >> 1, ako = (tid & 1) << 4;
  const float* aptr = Ap32 + (size_t)(bm * 128 + arow) * 1024 + ako;
  f32x4 acc[4][4] = {};

  float4 fA0 = *reinterpret_cast<const float4*>(aptr);
  float4 fA1 = *reinterpret_cast<const float4*>(aptr + 4);
  float4 fA2 = *reinterpret_cast<const float4*>(aptr + 8);
  float4 fA3 = *reinterpret_cast<const float4*>(aptr + 12);

  for (int kt = 0; kt < 1024; kt += 32) {
#pragma unroll
    for (int cc = 0; cc < 2; cc++) {
      int c = tid + cc * 256;
      int row = c >> 2, ko = (c & 3) << 3;
      gload_lds16(Bt + (size_t)(bn * 128 + row) * 1024 + kt + ko, Bs + c * 8);
    }
    {
      bf16x8 o0, o1;
      o0[0] = (bf16_t)fA0.x; o0[1] = (bf16_t)fA0.y; o0[2] = (bf16_t)fA0.z; o0[3] = (bf16_t)fA0.w;
      o0[4] = (bf16_t)fA1.x; o0[5] = (bf16_t)fA1.y; o0[6] = (bf16_t)fA1.z; o0[7] = (bf16_t)fA1.w;
      o1[0] = (bf16_t)fA2.x; o1[1] = (bf16_t)fA2.y; o1[2] = (bf16_t)fA2.z; o1[3] = (bf16_t)fA2.w;
      o1[4] = (bf16_t)fA3.x; o1[5] = (bf16_t)fA3.y; o1[6] = (bf16_t)fA3.z; o1[7] = (bf16_t)fA3.w;
      *reinterpret_cast<bf16x8*>(As + arow * 32 + ako) = o0;
      *reinterpret_cast<bf16x8*>(As + arow * 32 + ako + 8) = o1;
    }
    if (kt + 32 < 1024) {
      const float* np = aptr + kt + 32;
      fA0 = *reinterpret_cast<const float4*>(np);
      fA1 = *reinterpret_cast<const float4*>(np + 4);
      fA2 = *reinterpret_cast<const float4*>(np + 8);
      fA3 = *reinterpret_cast<const float4*>(np + 12);
    }
    __syncthreads();
    bf16x8 af[4], bfr[4];
#pragma unroll
    for (int t = 0; t < 4; t++)
      af[t] = *reinterpret_cast<const bf16x8*>(As + (wm + t * 16 + lr) * 32 + g * 8);
#pragma unroll
    for (int t = 0; t < 4; t++)
      bfr[t] = *reinterpret_cast<const bf16x8*>(Bs + (wn + t * 16 + lr) * 32 + g * 8);
    __builtin_amdgcn_s_setprio(1);
#pragma unroll
    for (int i = 0; i < 4; i++)
#pragma unroll
      for (int j = 0; j < 4; j++)
        acc[i][j] = __builtin_amdgcn_mfma_f32_16x16x32_bf16(af[i], bfr[j], acc[i][j], 0, 0, 0);
    __builtin_amdgcn_s_setprio(0);
    __syncthreads();
  }

#pragma unroll
  for (int i = 0; i < 4; i++)
#pragma unroll
    for (int j = 0; j < 4; j++)
#pragma unroll
      for (int e = 0; e < 4; e++) {
        int row = (bm << 7) + wm + i * 16 + g * 4 + e;       // b*SEQ + s
        int col = ((bn & 7) << 7) + wn + j * 16 + lr;        // h*64 + d
        float v = acc[i][j][e];
        int b = row >> 11, s = row & 2047, h = col >> 6, d = col & 63;
        size_t bh32 = (size_t)((b << 4) + h) * 32;
        if (pn == 0) {
          qh[((size_t)(((b << 4) + h) * SEQ + s) << 6) + d] = (bf16_t)v;
        } else if (pn == 1) {
          int kt2 = s >> 6, u = s & 63, t32 = u >> 5, ql2 = u & 31;
          int kk2 = d >> 4, hq2 = (d >> 3) & 1, e2 = d & 7;
          Kf[(bh32 + kt2) * 4096 + (t32 * 4 + kk2) * 512 + (hq2 * 32 + ql2) * 8 + e2] = (bf16_t)v;
        } else {
          int kt2 = s >> 6, u = s & 63, s2 = u >> 4, hq2 = (u >> 3) & 1, e2 = u & 7;
          int dkt = d >> 5, ql2 = d & 31;
          Vf[(bh32 + kt2) * 4096 + (dkt * 4 + s2) * 512 + (hq2 * 32 + ql2) * 8 + e2] = (bf16_t)v;
        }
      }
}

// ---------- WO GEMM: [4096x1024] x [1024x1024]^T -> fp32, 64x128 tiles ----------
__global__ __launch_bounds__(256)
void k_gemm_wo(const bf16_t* __restrict__ A, const bf16_t* __restrict__ Bt,
               float* __restrict__ C) {
  __shared__ __align__(16) bf16_t As[64 * 32];
  __shared__ __align__(16) bf16_t Bs[128 * 32];
  const int tid = threadIdx.x;
  const int lane = tid & 63, wave = tid >> 6;
  const int g = lane >> 4, lr = lane & 15;
  const int bm = blockIdx.x, bn = blockIdx.y;
  const int wm = (wave >> 1) << 5, wn = (wave & 1) << 6;
  f32x4 acc[2][4] = {};

  for (int kt = 0; kt < 1024; kt += 32) {
    {
      int row = tid >> 2, ko = (tid & 3) << 3;
      gload_lds16(A + (size_t)(bm * 64 + row) * 1024 + kt + ko, As + tid * 8);
    }
#pragma unroll
    for (int cc = 0; cc < 2; cc++) {
      int c = tid + cc * 256;
      int row = c >> 2, ko = (c & 3) << 3;
      gload_lds16(Bt + (size_t)(bn * 128 + row) * 1024 + kt + ko, Bs + c * 8);
    }
    __syncthreads();
    bf16x8 af[2], bfr[4];
#pragma unroll
    for (int t = 0; t < 2; t++)
      af[t] = *reinterpret_cast<const bf16x8*>(As + (wm + t * 16 + lr) * 32 + g * 8);
#pragma unroll
    for (int t = 0; t < 4; t++)
      bfr[t] = *reinterpret_cast<const bf16x8*>(Bs + (wn + t * 16 + lr) * 32 + g * 8);
    __builtin_amdgcn_s_setprio(1);
#pragma unroll
    for (int i = 0; i < 2; i++)
#pragma unroll
      for (int j = 0; j < 4; j++)
        acc[i][j] = __builtin_amdgcn_mfma_f32_16x16x32_bf16(af[i], bfr[j], acc[i][j], 0, 0, 0);
    __builtin_amdgcn_s_setprio(0);
    __syncthreads();
  }
#pragma unroll
  for (int i = 0; i < 2; i++)
#pragma unroll
    for (int j = 0; j < 4; j++)
#pragma unroll
      for (int e = 0; e < 4; e++) {
        int row = (bm << 6) + wm + i * 16 + g * 4 + e;
        int col = (bn << 7) + wn + j * 16 + lr;
        C[(size_t)row * D_MODEL + col] = acc[i][j][e];
      }
}

// ---------- flash attention v10: R10 body + mask as f32 MFMA C-operand ----------
// 1D grid 512 blocks, 512 thr = 8 waves: wave w = (kvhalf hh = w>>2)*4 + qw.
// bid&7 = XCD cluster (validated R10).  K/V double-buffered in LDS (R10).
// S = K*Q^T + mask computed by initializing the MFMA accumulator with the
// f32 fragment-ordered mask -> deletes 32 cvt + 32 add VALU/lane/iter.
// Next-iter mask loads issue right after QK consumes the current one
// (disjoint live ranges).
__global__ __launch_bounds__(512, 4)
void k_attn8(const bf16_t* __restrict__ Qh, const bf16_t* __restrict__ Kf,
             const bf16_t* __restrict__ Vf, const float* __restrict__ Mf,
             bf16_t* __restrict__ O) {
  __shared__ __align__(16) bf16_t Ks[2][2][4096];   // [kvhalf][buf][8 frags x 64 lanes x 8]
  __shared__ __align__(16) bf16_t Vs[2][2][4096];
  const int bid = blockIdx.x;
  const int xcd = bid & 7, loc = bid >> 3;
  const int bh = xcd * 4 + (loc >> 4);      // 4 bh per XCD
  const int qtile = loc & 15;
  const int b = bh >> 4, h = bh & 15;
  const int tid = threadIdx.x, w = tid >> 6, lane = tid & 63;
  const int qw = w & 3, hh = w >> 2;
  const int hq = lane >> 5, ql = lane & 31;
  const int tid256 = tid & 255;
  const int qbase = qtile * 128 + qw * 32;
  const bf16_t* qp = Qh + (size_t)bh * SEQ * DKH;
  const bf16_t* kfp = Kf + (size_t)bh * 32 * 4096;
  const bf16_t* vfp = Vf + (size_t)bh * 32 * 4096;
  const int qt = qtile * 4 + qw;
  const float* mpf = Mf + ((size_t)(qt * 32 + hh * 16) * 64 + lane) * 32;
  const int NIT = 16;

  bf16x8 aq[4];
#pragma unroll
  for (int kk = 0; kk < 4; kk++)
    aq[kk] = *reinterpret_cast<const bf16x8*>(
        qp + (size_t)(qbase + ql) * DKH + kk * 16 + hq * 8);

  f32x16 oacc[2] = {};
  float lsum = 0.f;

  auto stage = [&](int buf, int kt) {
#pragma unroll
    for (int cc = 0; cc < 2; cc++) {
      int c = tid256 + cc * 256;        // 512 16B-units per tile, fully linear
      gload_lds16(kfp + (size_t)kt * 4096 + c * 8, &Ks[hh][buf][c * 8]);
      gload_lds16(vfp + (size_t)kt * 4096 + c * 8, &Vs[hh][buf][c * 8]);
    }
  };

  stage(0, hh * 16);
  f32x16 mvA = ld16f(mpf);          // mask for it=0 (t32=0 / t32=1 halves)
  f32x16 mvB = ld16f(mpf + 16);
  __syncthreads();

  for (int it = 0; it < NIT; ++it) {
    const int cur = it & 1;
    if (it + 1 < NIT) stage(cur ^ 1, hh * 16 + it + 1);

    const bf16_t* kb = Ks[hh][cur];
    const bf16_t* vb = Vs[hh][cur];

    // S^T = K Q^T + mask : accumulator initialized with the f32 mask fragment
    f32x16 p[2];
    p[0] = mvA;
    p[1] = mvB;
#pragma unroll
    for (int t32 = 0; t32 < 2; t32++) {
      __builtin_amdgcn_s_setprio(1);
#pragma unroll
      for (int kk = 0; kk < 4; kk++) {
        bf16x8 bk = *reinterpret_cast<const bf16x8*>(kb + (t32 * 4 + kk) * 512 + lane * 8);
        p[t32] = __builtin_amdgcn_mfma_f32_32x32x16_bf16(bk, aq[kk], p[t32], 0, 0, 0);
      }
      __builtin_amdgcn_s_setprio(0);
    }

    // issue next iter's mask loads now (mv dead, ~1000cy to cover L2 latency)
    {
      const float* mn = mpf + (size_t)((it + 1 < NIT) ? (it + 1) : it) * 2048;
      mvA = ld16f(mn);
      mvB = ld16f(mn + 16);
    }

    // exp2 -> pack to PV A-frags via permlane32_swap (validated R7)
    bf16x8 paf[4];
#pragma unroll
    for (int s = 0; s < 4; s++) {
      const int t32 = s >> 1, rb = (s & 1) * 8;
      float pes[8];
#pragma unroll
      for (int j = 0; j < 8; j++) {
        float pe = fast_exp2(p[t32][rb + j]);
        lsum += pe;
        pes[j] = pe;
      }
      uint32_t u0 = pkbf(pes[0], pes[1]), u1 = pkbf(pes[2], pes[3]);
      uint32_t w0 = pkbf(pes[4], pes[5]), w1 = pkbf(pes[6], pes[7]);
      perm32swap(u0, w0);          // low-kv word FIRST (vdst), high second
      perm32swap(u1, w1);
      union { uint32_t wd[4]; bf16x8 v8; } fu;
      fu.wd[0] = u0; fu.wd[1] = u1; fu.wd[2] = w0; fu.wd[3] = w1;
      paf[s] = fu.v8;
    }

    // O += P V : A = paf (k-slot kv = 16s+8*hq+e), B = V frag (dkt*4+s)
#pragma unroll
    for (int dkt = 0; dkt < 2; dkt++) {
      __builtin_amdgcn_s_setprio(1);
#pragma unroll
      for (int s = 0; s < 4; s++) {
        bf16x8 bv = *reinterpret_cast<const bf16x8*>(vb + (dkt * 4 + s) * 512 + lane * 8);
        oacc[dkt] = __builtin_amdgcn_mfma_f32_32x32x16_bf16(paf[s], bv, oacc[dkt], 0, 0, 0);
      }
      __builtin_amdgcn_s_setprio(0);
    }
    __syncthreads();
  }

  // merge kv-halves via LDS (reuse Ks/Vs), then normalize + write (validated R8)
  float* smO = (float*)&Ks[0][0][0];   // 32 KB
  float* smL = (float*)&Vs[0][0][0];
  if (w >= 4) {
    int base = (qw * 64 + lane) * 32;
#pragma unroll
    for (int dkt = 0; dkt < 2; dkt++)
#pragma unroll
      for (int cg = 0; cg < 4; cg++) {
        int chs = ((dkt * 4 + cg) ^ (lane & 7)) * 4;
        float4 val = {oacc[dkt][cg * 4], oacc[dkt][cg * 4 + 1],
                      oacc[dkt][cg * 4 + 2], oacc[dkt][cg * 4 + 3]};
        *reinterpret_cast<float4*>(&smO[base + chs]) = val;
      }
    smL[qw * 64 + lane] = lsum;
  }
  __syncthreads();
  if (w < 4) {
    int base = (qw * 64 + lane) * 32;
#pragma unroll
    for (int dkt = 0; dkt < 2; dkt++)
#pragma unroll
      for (int cg = 0; cg < 4; cg++) {
        int chs = ((dkt * 4 + cg) ^ (lane & 7)) * 4;
        float4 pv = *reinterpret_cast<const float4*>(&smO[base + chs]);
#pragma unroll
        for (int e = 0; e < 4; e++) oacc[dkt][cg * 4 + e] += pv[e];
      }
    lsum += smL[qw * 64 + lane];
    float lf = lsum + __shfl_xor(lsum, 32);   // full row-sum for q = qbase+ql
    float inv[16];
#pragma unroll
    for (int reg = 0; reg < 16; reg++) {
      int qrow = (reg & 3) + 8 * (reg >> 2) + 4 * hq;
      inv[reg] = 1.0f / __shfl(lf, qrow);
    }
#pragma unroll
    for (int dkt = 0; dkt < 2; dkt++)
#pragma unroll
      for (int reg = 0; reg < 16; reg++) {
        int qrow = (reg & 3) + 8 * (reg >> 2) + 4 * hq;
        float v = oacc[dkt][reg] * inv[reg];
        O[(size_t)(b * SEQ + qbase + qrow) * D_MODEL + (h << 6) + dkt * 32 + ql] = (bf16_t)v;
      }
  }
}

extern "C" void kernel_launch(void* const* d_in, const int* in_sizes, int n_in,
                              void* d_out, int out_size, void* d_ws, size_t ws_size,
                              hipStream_t stream) {
  const float* Q  = (const float*)d_in[0];
  const float* K  = (const float*)d_in[1];
  const float* V  = (const float*)d_in[2];
  const float* M  = (const float*)d_in[3];
  const float* WQ = (const float*)d_in[5];
  const float* WK = (const float*)d_in[6];
  const float* WV = (const float*)d_in[7];
  const float* WO = (const float*)d_in[8];

  char* ws = (char*)d_ws;
  const size_t MB = 1 << 20;
  float*  Mff   = (float*)(ws + 0 * MB);     // 16 MB f32 fragment-order mask
  bf16_t* WqkvT = (bf16_t*)(ws + 32 * MB);   // 6 MB [3072][1024]
  bf16_t* WoT   = (bf16_t*)(ws + 38 * MB);   // 2 MB (contiguous after WqkvT)
  bf16_t* qh    = (bf16_t*)(ws + 40 * MB);   // [B,H,S,dk]
  bf16_t* Kf    = (bf16_t*)(ws + 48 * MB);   // 8 MB K fragment-order
  bf16_t* Vf    = (bf16_t*)(ws + 56 * MB);   // 8 MB V fragment-order
  bf16_t* Ob    = (bf16_t*)(ws + 64 * MB);   // [B,S,H*dk]

  k_maskg<<<4096, 256, 0, stream>>>(M, Mff);
  k_cvtw<<<16384, 256, 0, stream>>>(WQ, WK, WV, WO, WqkvT);

  k_gemm_qkv<<<dim3(32, 24), 256, 0, stream>>>(Q, K, V, WqkvT, qh, Kf, Vf);

  k_attn8<<<512, 512, 0, stream>>>(qh, Kf, Vf, Mff, Ob);

  k_gemm_wo<<<dim3(64, 8), 256, 0, stream>>>(Ob, WoT, (float*)d_out);
}

// Round 13
// 167.577 us; speedup vs baseline: 1.7795x; 1.0531x over previous
//
#include <hip/hip_runtime.h>
#include <hip/hip_bf16.h>
#include <stdint.h>

#define D_MODEL 1024
#define NHEAD 16
#define DKH 64
#define BATCH 2
#define SEQ 2048
#define LOG2E 1.44269504088896f

typedef __bf16 bf16_t;
typedef __bf16 bf16x8 __attribute__((ext_vector_type(8)));
typedef float f32x4 __attribute__((ext_vector_type(4)));
typedef float f32x16 __attribute__((ext_vector_type(16)));

__device__ __forceinline__ float fast_exp2(float x) {
#if __has_builtin(__builtin_amdgcn_exp2f)
  return __builtin_amdgcn_exp2f(x);
#else
  return exp2f(x);
#endif
}

// ---------- async global->LDS (16B per lane) ----------
__device__ __forceinline__ void gload_lds16(const bf16_t* g, bf16_t* l) {
  auto gp = (const __attribute__((address_space(1))) void*)(uintptr_t)g;
  auto lp = (__attribute__((address_space(3))) void*)(uintptr_t)l;
  __builtin_amdgcn_global_load_lds(gp, lp, 16, 0, 0);
}

// pack two f32 -> u32 of 2 bf16 (compiler emits v_cvt_pk_bf16_f32)
__device__ __forceinline__ uint32_t pkbf(float lo, float hi) {
  bf16_t a = (bf16_t)lo, c = (bf16_t)hi;
  uint16_t ua, uc;
  __builtin_memcpy(&ua, &a, 2);
  __builtin_memcpy(&uc, &c, 2);
  return (uint32_t)ua | ((uint32_t)uc << 16);
}

// v_permlane32_swap_b32 a, b: swaps a.lanes[32:63] <-> b.lanes[0:31]
// Call as perm32swap(low_kv_word, high_kv_word). (validated R7)
__device__ __forceinline__ void perm32swap(uint32_t& a, uint32_t& b) {
  asm volatile("v_permlane32_swap_b32 %0, %1" : "+v"(a), "+v"(b));
}

// Fused weight conversion.  n<3072: WqkvT[n][d] (Q scaled by 0.125*log2e);
// n>=3072: WoT[n-3072][d] = WO[d][n-3072].
__global__ void k_cvtw(const float* __restrict__ WQ, const float* __restrict__ WK,
                       const float* __restrict__ WV, const float* __restrict__ WO,
                       bf16_t* __restrict__ wt) {
  int j = blockIdx.x * 256 + threadIdx.x;        // 4M outputs
  int d = j & 1023, n = j >> 10;
  if (n < 3072) {
    int proj = n >> 10, h = (n >> 6) & 15, k = n & 63;
    const float* w = proj == 0 ? WQ : (proj == 1 ? WK : WV);
    float scale = proj == 0 ? (0.125f * LOG2E) : 1.0f;
    wt[j] = (bf16_t)(w[(h << 16) + (d << 6) + k] * scale);
  } else {
    wt[j] = (bf16_t)WO[(d << 10) + (n - 3072)];
  }
}

// Mask pre-gather for 32x32 swapped-QK D-layout, scaled by log2e, bf16
// (validated R7/R10; bf16 keeps the per-kvt L2 slice at 256KB — R12 lesson).
__global__ void k_maskg(const float* __restrict__ M, bf16_t* __restrict__ Mf) {
  int t = blockIdx.x * 256 + threadIdx.x;        // 1M threads, 4 vals each
  int wch = t & 7, lane = (t >> 3) & 63;
  int kvt = (t >> 9) & 31, qt = t >> 14;
  int h = lane >> 5, ql = lane & 31;
  int q = qt * 32 + ql;
  int t32 = wch >> 2, r2 = wch & 3;
  int kvb = kvt * 64 + t32 * 32 + 8 * r2 + 4 * h;
  float4 m4 = *reinterpret_cast<const float4*>(M + (size_t)q * SEQ + kvb);
  bf16_t o[4];
  o[0] = (bf16_t)(m4.x * LOG2E); o[1] = (bf16_t)(m4.y * LOG2E);
  o[2] = (bf16_t)(m4.z * LOG2E); o[3] = (bf16_t)(m4.w * LOG2E);
  *reinterpret_cast<ushort4*>(Mf + (size_t)t * 4) = *reinterpret_cast<ushort4*>(o);
}

// ---------- fused QKV projection GEMM, f32 A inputs converted in-staging ----------
__global__ __launch_bounds__(256)
void k_gemm_qkv(const float* __restrict__ Qs, const float* __restrict__ Ks32,
                const float* __restrict__ Vs32, const bf16_t* __restrict__ Bt,
                bf16_t* __restrict__ qh, bf16_t* __restrict__ Kf,
                bf16_t* __restrict__ Vf) {
  __shared__ __align__(16) bf16_t As[128 * 32];
  __shared__ __align__(16) bf16_t Bs[128 * 32];
  const int tid = threadIdx.x;
  const int lane = tid & 63, wave = tid >> 6;
  const int g = lane >> 4, lr = lane & 15;
  const int bm = blockIdx.x, bn = blockIdx.y;
  const int pn = bn >> 3;   // 0:q 1:k 2:v  (block-uniform)
  const float* Ap32 = pn == 0 ? Qs : (pn == 1 ? Ks32 : Vs32);
  const int wm = (wave >> 1) << 6, wn = (wave & 1) << 6;
  const int arow = tid >> 1, ako = (tid & 1) << 4;
  const float* aptr = Ap32 + (size_t)(bm * 128 + arow) * 1024 + ako;
  f32x4 acc[4][4] = {};

  float4 fA0 = *reinterpret_cast<const float4*>(aptr);
  float4 fA1 = *reinterpret_cast<const float4*>(aptr + 4);
  float4 fA2 = *reinterpret_cast<const float4*>(aptr + 8);
  float4 fA3 = *reinterpret_cast<const float4*>(aptr + 12);

  for (int kt = 0; kt < 1024; kt += 32) {
#pragma unroll
    for (int cc = 0; cc < 2; cc++) {
      int c = tid + cc * 256;
      int row = c >> 2, ko = (c & 3) << 3;
      gload_lds16(Bt + (size_t)(bn * 128 + row) * 1024 + kt + ko, Bs + c * 8);
    }
    {
      bf16x8 o0, o1;
      o0[0] = (bf16_t)fA0.x; o0[1] = (bf16_t)fA0.y; o0[2] = (bf16_t)fA0.z; o0[3] = (bf16_t)fA0.w;
      o0[4] = (bf16_t)fA1.x; o0[5] = (bf16_t)fA1.y; o0[6] = (bf16_t)fA1.z; o0[7] = (bf16_t)fA1.w;
      o1[0] = (bf16_t)fA2.x; o1[1] = (bf16_t)fA2.y; o1[2] = (bf16_t)fA2.z; o1[3] = (bf16_t)fA2.w;
      o1[4] = (bf16_t)fA3.x; o1[5] = (bf16_t)fA3.y; o1[6] = (bf16_t)fA3.z; o1[7] = (bf16_t)fA3.w;
      *reinterpret_cast<bf16x8*>(As + arow * 32 + ako) = o0;
      *reinterpret_cast<bf16x8*>(As + arow * 32 + ako + 8) = o1;
    }
    if (kt + 32 < 1024) {
      const float* np = aptr + kt + 32;
      fA0 = *reinterpret_cast<const float4*>(np);
      fA1 = *reinterpret_cast<const float4*>(np + 4);
      fA2 = *reinterpret_cast<const float4*>(np + 8);
      fA3 = *reinterpret_cast<const float4*>(np + 12);
    }
    __syncthreads();
    bf16x8 af[4], bfr[4];
#pragma unroll
    for (int t = 0; t < 4; t++)
      af[t] = *reinterpret_cast<const bf16x8*>(As + (wm + t * 16 + lr) * 32 + g * 8);
#pragma unroll
    for (int t = 0; t < 4; t++)
      bfr[t] = *reinterpret_cast<const bf16x8*>(Bs + (wn + t * 16 + lr) * 32 + g * 8);
    __builtin_amdgcn_s_setprio(1);
#pragma unroll
    for (int i = 0; i < 4; i++)
#pragma unroll
      for (int j = 0; j < 4; j++)
        acc[i][j] = __builtin_amdgcn_mfma_f32_16x16x32_bf16(af[i], bfr[j], acc[i][j], 0, 0, 0);
    __builtin_amdgcn_s_setprio(0);
    __syncthreads();
  }

#pragma unroll
  for (int i = 0; i < 4; i++)
#pragma unroll
    for (int j = 0; j < 4; j++)
#pragma unroll
      for (int e = 0; e < 4; e++) {
        int row = (bm << 7) + wm + i * 16 + g * 4 + e;       // b*SEQ + s
        int col = ((bn & 7) << 7) + wn + j * 16 + lr;        // h*64 + d
        float v = acc[i][j][e];
        int b = row >> 11, s = row & 2047, h = col >> 6, d = col & 63;
        size_t bh32 = (size_t)((b << 4) + h) * 32;
        if (pn == 0) {
          qh[((size_t)(((b << 4) + h) * SEQ + s) << 6) + d] = (bf16_t)v;
        } else if (pn == 1) {
          int kt2 = s >> 6, u = s & 63, t32 = u >> 5, ql2 = u & 31;
          int kk2 = d >> 4, hq2 = (d >> 3) & 1, e2 = d & 7;
          Kf[(bh32 + kt2) * 4096 + (t32 * 4 + kk2) * 512 + (hq2 * 32 + ql2) * 8 + e2] = (bf16_t)v;
        } else {
          int kt2 = s >> 6, u = s & 63, s2 = u >> 4, hq2 = (u >> 3) & 1, e2 = u & 7;
          int dkt = d >> 5, ql2 = d & 31;
          Vf[(bh32 + kt2) * 4096 + (dkt * 4 + s2) * 512 + (hq2 * 32 + ql2) * 8 + e2] = (bf16_t)v;
        }
      }
}

// ---------- WO GEMM: [4096x1024] x [1024x1024]^T -> fp32, 64x128 tiles ----------
__global__ __launch_bounds__(256)
void k_gemm_wo(const bf16_t* __restrict__ A, const bf16_t* __restrict__ Bt,
               float* __restrict__ C) {
  __shared__ __align__(16) bf16_t As[64 * 32];
  __shared__ __align__(16) bf16_t Bs[128 * 32];
  const int tid = threadIdx.x;
  const int lane = tid & 63, wave = tid >> 6;
  const int g = lane >> 4, lr = lane & 15;
  const int bm = blockIdx.x, bn = blockIdx.y;
  const int wm = (wave >> 1) << 5, wn = (wave & 1) << 6;
  f32x4 acc[2][4] = {};

  for (int kt = 0; kt < 1024; kt += 32) {
    {
      int row = tid >> 2, ko = (tid & 3) << 3;
      gload_lds16(A + (size_t)(bm * 64 + row) * 1024 + kt + ko, As + tid * 8);
    }
#pragma unroll
    for (int cc = 0; cc < 2; cc++) {
      int c = tid + cc * 256;
      int row = c >> 2, ko = (c & 3) << 3;
      gload_lds16(Bt + (size_t)(bn * 128 + row) * 1024 + kt + ko, Bs + c * 8);
    }
    __syncthreads();
    bf16x8 af[2], bfr[4];
#pragma unroll
    for (int t = 0; t < 2; t++)
      af[t] = *reinterpret_cast<const bf16x8*>(As + (wm + t * 16 + lr) * 32 + g * 8);
#pragma unroll
    for (int t = 0; t < 4; t++)
      bfr[t] = *reinterpret_cast<const bf16x8*>(Bs + (wn + t * 16 + lr) * 32 + g * 8);
    __builtin_amdgcn_s_setprio(1);
#pragma unroll
    for (int i = 0; i < 2; i++)
#pragma unroll
      for (int j = 0; j < 4; j++)
        acc[i][j] = __builtin_amdgcn_mfma_f32_16x16x32_bf16(af[i], bfr[j], acc[i][j], 0, 0, 0);
    __builtin_amdgcn_s_setprio(0);
    __syncthreads();
  }
#pragma unroll
  for (int i = 0; i < 2; i++)
#pragma unroll
    for (int j = 0; j < 4; j++)
#pragma unroll
      for (int e = 0; e < 4; e++) {
        int row = (bm << 6) + wm + i * 16 + g * 4 + e;
        int col = (bn << 7) + wn + j * 16 + lr;
        C[(size_t)row * D_MODEL + col] = acc[i][j][e];
      }
}

// ---------- flash attention v11: R10 body, V read direct from L2 ----------
// 1D grid 512 blocks, 512 thr = 8 waves: wave w = (kvhalf hh = w>>2)*4 + qw.
// bid&7 = XCD cluster (validated R10): per-XCD V hot set = 4bh x 512KB = 2MB,
// L2-resident -> V skips LDS (fragment-ordered global, linear imm-offset
// dwordx4 loads issued after QK; softmax covers L2 latency).  LDS 64->36KB.
// launch_bounds(512,4): 128-reg cap, NO spill (R11's (512,6) was the bug).
__global__ __launch_bounds__(512, 4)
void k_attn9(const bf16_t* __restrict__ Qh, const bf16_t* __restrict__ Kf,
             const bf16_t* __restrict__ Vf, const bf16_t* __restrict__ Mf,
             bf16_t* __restrict__ O) {
  __shared__ __align__(16) char smem[36864];   // Ks[2][2][4096]b16 (32KB) | merge
  bf16_t* KsB = reinterpret_cast<bf16_t*>(smem);
  const int bid = blockIdx.x;
  const int xcd = bid & 7, loc = bid >> 3;
  const int bh = xcd * 4 + (loc >> 4);      // 4 bh per XCD
  const int qtile = loc & 15;
  const int b = bh >> 4, h = bh & 15;
  const int tid = threadIdx.x, w = tid >> 6, lane = tid & 63;
  const int qw = w & 3, hh = w >> 2;
  const int hq = lane >> 5, ql = lane & 31;
  const int tid256 = tid & 255;
  const int qbase = qtile * 128 + qw * 32;
  const bf16_t* qp = Qh + (size_t)bh * SEQ * DKH;
  const bf16_t* kfp = Kf + (size_t)bh * 32 * 4096;
  const bf16_t* vfp = Vf + (size_t)bh * 32 * 4096;
  const int qt = qtile * 4 + qw;
  const bf16_t* mp = Mf + ((size_t)(qt * 32 + hh * 16) * 64 + lane) * 32;
  const int NIT = 16;

  bf16x8 aq[4];
#pragma unroll
  for (int kk = 0; kk < 4; kk++)
    aq[kk] = *reinterpret_cast<const bf16x8*>(
        qp + (size_t)(qbase + ql) * DKH + kk * 16 + hq * 8);

  f32x16 oacc[2] = {};
  float lsum = 0.f;

  auto stage = [&](int buf, int kt) {
#pragma unroll
    for (int cc = 0; cc < 2; cc++) {
      int c = tid256 + cc * 256;        // 512 16B-units of the K tile, linear
      gload_lds16(kfp + (size_t)kt * 4096 + c * 8,
                  KsB + (hh * 2 + buf) * 4096 + c * 8);
    }
  };

  stage(0, hh * 16);
  bf16x8 mv[4];
#pragma unroll
  for (int j = 0; j < 4; j++)
    mv[j] = *reinterpret_cast<const bf16x8*>(mp + j * 8);
  __syncthreads();

  for (int it = 0; it < NIT; ++it) {
    const int cur = it & 1;
    if (it + 1 < NIT) stage(cur ^ 1, hh * 16 + it + 1);

    const bf16_t* kb = KsB + (hh * 2 + cur) * 4096;
    const bf16_t* vt = vfp + (size_t)(hh * 16 + it) * 4096 + lane * 8;

    // S^T = K Q^T : D[kv 32 rows][q = ql], rows = (reg&3)+8*(reg>>2)+4*hq
    f32x16 p[2];
#pragma unroll
    for (int t32 = 0; t32 < 2; t32++) {
      f32x16 a = {};
      __builtin_amdgcn_s_setprio(1);
#pragma unroll
      for (int kk = 0; kk < 4; kk++) {
        bf16x8 bk = *reinterpret_cast<const bf16x8*>(kb + (t32 * 4 + kk) * 512 + lane * 8);
        a = __builtin_amdgcn_mfma_f32_32x32x16_bf16(bk, aq[kk], a, 0, 0, 0);
      }
      __builtin_amdgcn_s_setprio(0);
      p[t32] = a;
    }

    // issue V fragment loads now (L2-resident; softmax below covers latency)
    bf16x8 bv[8];
#pragma unroll
    for (int s = 0; s < 8; s++)
      bv[s] = *reinterpret_cast<const bf16x8*>(vt + s * 512);

    // mask + exp2 -> pack to PV A-frags via permlane32_swap (validated R7)
    bf16x8 paf[4];
#pragma unroll
    for (int s = 0; s < 4; s++) {
      const int t32 = s >> 1, rb = (s & 1) * 8;
      float pes[8];
#pragma unroll
      for (int j = 0; j < 8; j++) {
        int v = t32 * 16 + rb + j;
        float x = p[t32][rb + j] + (float)mv[v >> 3][v & 7];
        float pe = fast_exp2(x);
        lsum += pe;
        pes[j] = pe;
      }
      uint32_t u0 = pkbf(pes[0], pes[1]), u1 = pkbf(pes[2], pes[3]);
      uint32_t w0 = pkbf(pes[4], pes[5]), w1 = pkbf(pes[6], pes[7]);
      perm32swap(u0, w0);          // low-kv word FIRST (vdst), high second
      perm32swap(u1, w1);
      union { uint32_t wd[4]; bf16x8 v8; } fu;
      fu.wd[0] = u0; fu.wd[1] = u1; fu.wd[2] = w0; fu.wd[3] = w1;
      paf[s] = fu.v8;
    }

    // prefetch next iter's mask (consumed after the barrier)
    {
      const bf16_t* mn = mp + (size_t)((it + 1 < NIT) ? (it + 1) : it) * 2048;
#pragma unroll
      for (int j = 0; j < 4; j++)
        mv[j] = *reinterpret_cast<const bf16x8*>(mn + j * 8);
    }

    // O += P V : A = paf (k-slot kv = 16s+8*hq+e), B = V frag (dkt*4+s)
#pragma unroll
    for (int dkt = 0; dkt < 2; dkt++) {
      __builtin_amdgcn_s_setprio(1);
#pragma unroll
      for (int s = 0; s < 4; s++)
        oacc[dkt] = __builtin_amdgcn_mfma_f32_32x32x16_bf16(paf[s], bv[dkt * 4 + s], oacc[dkt], 0, 0, 0);
      __builtin_amdgcn_s_setprio(0);
    }
    __syncthreads();
  }

  // merge kv-halves via LDS union, normalize + write (validated R8)
  float* smO = (float*)smem;                    // 32 KB
  float* smL = (float*)(smem + 32768);          // 1 KB
  if (w >= 4) {
    int base = (qw * 64 + lane) * 32;
#pragma unroll
    for (int dkt = 0; dkt < 2; dkt++)
#pragma unroll
      for (int cg = 0; cg < 4; cg++) {
        int chs = ((dkt * 4 + cg) ^ (lane & 7)) * 4;
        float4 val = {oacc[dkt][cg * 4], oacc[dkt][cg * 4 + 1],
                      oacc[dkt][cg * 4 + 2], oacc[dkt][cg * 4 + 3]};
        *reinterpret_cast<float4*>(&smO[base + chs]) = val;
      }
    smL[qw * 64 + lane] = lsum;
  }
  __syncthreads();
  if (w < 4) {
    int base = (qw * 64 + lane) * 32;
#pragma unroll
    for (int dkt = 0; dkt < 2; dkt++)
#pragma unroll
      for (int cg = 0; cg < 4; cg++) {
        int chs = ((dkt * 4 + cg) ^ (lane & 7)) * 4;
        float4 pv = *reinterpret_cast<const float4*>(&smO[base + chs]);
#pragma unroll
        for (int e = 0; e < 4; e++) oacc[dkt][cg * 4 + e] += pv[e];
      }
    lsum += smL[qw * 64 + lane];
    float lf = lsum + __shfl_xor(lsum, 32);   // full row-sum for q = qbase+ql
    float inv[16];
#pragma unroll
    for (int reg = 0; reg < 16; reg++) {
      int qrow = (reg & 3) + 8 * (reg >> 2) + 4 * hq;
      inv[reg] = 1.0f / __shfl(lf, qrow);
    }
#pragma unroll
    for (int dkt = 0; dkt < 2; dkt++)
#pragma unroll
      for (int reg = 0; reg < 16; reg++) {
        int qrow = (reg & 3) + 8 * (reg >> 2) + 4 * hq;
        float v = oacc[dkt][reg] * inv[reg];
        O[(size_t)(b * SEQ + qbase + qrow) * D_MODEL + (h << 6) + dkt * 32 + ql] = (bf16_t)v;
      }
  }
}

extern "C" void kernel_launch(void* const* d_in, const int* in_sizes, int n_in,
                              void* d_out, int out_size, void* d_ws, size_t ws_size,
                              hipStream_t stream) {
  const float* Q  = (const float*)d_in[0];
  const float* K  = (const float*)d_in[1];
  const float* V  = (const float*)d_in[2];
  const float* M  = (const float*)d_in[3];
  const float* WQ = (const float*)d_in[5];
  const float* WK = (const float*)d_in[6];
  const float* WV = (const float*)d_in[7];
  const float* WO = (const float*)d_in[8];

  char* ws = (char*)d_ws;
  const size_t MB = 1 << 20;
  bf16_t* Mf    = (bf16_t*)(ws + 24 * MB);   // 8 MB bf16 fragment-order mask
  bf16_t* WqkvT = (bf16_t*)(ws + 32 * MB);   // 6 MB [3072][1024]
  bf16_t* WoT   = (bf16_t*)(ws + 38 * MB);   // 2 MB (contiguous after WqkvT)
  bf16_t* qh    = (bf16_t*)(ws + 40 * MB);   // [B,H,S,dk]
  bf16_t* Kf    = (bf16_t*)(ws + 48 * MB);   // 8 MB K fragment-order
  bf16_t* Vf    = (bf16_t*)(ws + 56 * MB);   // 8 MB V fragment-order
  bf16_t* Ob    = (bf16_t*)(ws + 64 * MB);   // [B,S,H*dk]

  k_maskg<<<4096, 256, 0, stream>>>(M, Mf);
  k_cvtw<<<16384, 256, 0, stream>>>(WQ, WK, WV, WO, WqkvT);

  k_gemm_qkv<<<dim3(32, 24), 256, 0, stream>>>(Q, K, V, WqkvT, qh, Kf, Vf);

  k_attn9<<<512, 512, 0, stream>>>(qh, Kf, Vf, Mf, Ob);

  k_gemm_wo<<<dim3(64, 8), 256, 0, stream>>>(Ob, WoT, (float*)d_out);
}

// Round 14
// 149.998 us; speedup vs baseline: 1.9881x; 1.1172x over previous
//
#include <hip/hip_runtime.h>
#include <hip/hip_bf16.h>
#include <stdint.h>

#define D_MODEL 1024
#define NHEAD 16
#define DKH 64
#define BATCH 2
#define SEQ 2048
#define LOG2E 1.44269504088896f

typedef __bf16 bf16_t;
typedef __bf16 bf16x8 __attribute__((ext_vector_type(8)));
typedef float f32x4 __attribute__((ext_vector_type(4)));
typedef float f32x16 __attribute__((ext_vector_type(16)));

__device__ __forceinline__ float fast_exp2(float x) {
#if __has_builtin(__builtin_amdgcn_exp2f)
  return __builtin_amdgcn_exp2f(x);
#else
  return exp2f(x);
#endif
}

// ---------- async global->LDS (16B per lane) ----------
__device__ __forceinline__ void gload_lds16(const bf16_t* g, bf16_t* l) {
  auto gp = (const __attribute__((address_space(1))) void*)(uintptr_t)g;
  auto lp = (__attribute__((address_space(3))) void*)(uintptr_t)l;
  __builtin_amdgcn_global_load_lds(gp, lp, 16, 0, 0);
}

// pack two f32 -> u32 of 2 bf16 (compiler emits v_cvt_pk_bf16_f32)
__device__ __forceinline__ uint32_t pkbf(float lo, float hi) {
  bf16_t a = (bf16_t)lo, c = (bf16_t)hi;
  uint16_t ua, uc;
  __builtin_memcpy(&ua, &a, 2);
  __builtin_memcpy(&uc, &c, 2);
  return (uint32_t)ua | ((uint32_t)uc << 16);
}

// v_permlane32_swap_b32 a, b: swaps a.lanes[32:63] <-> b.lanes[0:31]
// Call as perm32swap(low_kv_word, high_kv_word). (validated R7)
__device__ __forceinline__ void perm32swap(uint32_t& a, uint32_t& b) {
  asm volatile("v_permlane32_swap_b32 %0, %1" : "+v"(a), "+v"(b));
}

// Fused weight conversion.  n<3072: WqkvT[n][d] (Q scaled by 0.125*log2e);
// n>=3072: WoT[n-3072][d] = WO[d][n-3072].
__global__ void k_cvtw(const float* __restrict__ WQ, const float* __restrict__ WK,
                       const float* __restrict__ WV, const float* __restrict__ WO,
                       bf16_t* __restrict__ wt) {
  int j = blockIdx.x * 256 + threadIdx.x;        // 4M outputs
  int d = j & 1023, n = j >> 10;
  if (n < 3072) {
    int proj = n >> 10, h = (n >> 6) & 15, k = n & 63;
    const float* w = proj == 0 ? WQ : (proj == 1 ? WK : WV);
    float scale = proj == 0 ? (0.125f * LOG2E) : 1.0f;
    wt[j] = (bf16_t)(w[(h << 16) + (d << 6) + k] * scale);
  } else {
    wt[j] = (bf16_t)WO[(d << 10) + (n - 3072)];
  }
}

// Mask pre-gather for 32x32 swapped-QK D-layout, scaled by log2e, bf16 (validated R7/R10)
__global__ void k_maskg(const float* __restrict__ M, bf16_t* __restrict__ Mf) {
  int t = blockIdx.x * 256 + threadIdx.x;        // 1M threads, 4 vals each
  int wch = t & 7, lane = (t >> 3) & 63;
  int kvt = (t >> 9) & 31, qt = t >> 14;
  int h = lane >> 5, ql = lane & 31;
  int q = qt * 32 + ql;
  int t32 = wch >> 2, r2 = wch & 3;
  int kvb = kvt * 64 + t32 * 32 + 8 * r2 + 4 * h;
  float4 m4 = *reinterpret_cast<const float4*>(M + (size_t)q * SEQ + kvb);
  bf16_t o[4];
  o[0] = (bf16_t)(m4.x * LOG2E); o[1] = (bf16_t)(m4.y * LOG2E);
  o[2] = (bf16_t)(m4.z * LOG2E); o[3] = (bf16_t)(m4.w * LOG2E);
  *reinterpret_cast<ushort4*>(Mf + (size_t)t * 4) = *reinterpret_cast<ushort4*>(o);
}

// ---------- fused QKV projection GEMM, 128x256 tiles, f32 A converted in-staging ----
// grid (32, 12); pn = bn>>2 selects input + epilogue; 4 waves, each 64x128 out
// (acc 4x8).  A re-read per projection drops 8x -> 4x (384->192 MB via L3).
__global__ __launch_bounds__(256, 2)
void k_gemm_qkv(const float* __restrict__ Qs, const float* __restrict__ Ks32,
                const float* __restrict__ Vs32, const bf16_t* __restrict__ Bt,
                bf16_t* __restrict__ qh, bf16_t* __restrict__ Kf,
                bf16_t* __restrict__ Vf) {
  __shared__ __align__(16) bf16_t As[128 * 32];   // 8 KB
  __shared__ __align__(16) bf16_t Bs[256 * 32];   // 16 KB
  const int tid = threadIdx.x;
  const int lane = tid & 63, wave = tid >> 6;
  const int g = lane >> 4, lr = lane & 15;
  const int bm = blockIdx.x, bn = blockIdx.y;
  const int pn = bn >> 2;   // 0:q 1:k 2:v  (block-uniform)
  const int bnl = bn & 3;   // 256-col tile within projection
  const float* Ap32 = pn == 0 ? Qs : (pn == 1 ? Ks32 : Vs32);
  const int wm = (wave >> 1) << 6, wn = (wave & 1) << 7;
  const int arow = tid >> 1, ako = (tid & 1) << 4;
  const float* aptr = Ap32 + (size_t)(bm * 128 + arow) * 1024 + ako;
  f32x4 acc[4][8] = {};

  float4 fA0 = *reinterpret_cast<const float4*>(aptr);
  float4 fA1 = *reinterpret_cast<const float4*>(aptr + 4);
  float4 fA2 = *reinterpret_cast<const float4*>(aptr + 8);
  float4 fA3 = *reinterpret_cast<const float4*>(aptr + 12);

  for (int kt = 0; kt < 1024; kt += 32) {
    // B staging: 256x32 tile = 1024 8-elem chunks, 4 per thread
#pragma unroll
    for (int cc = 0; cc < 4; cc++) {
      int c = tid + cc * 256;
      int row = c >> 2, ko = (c & 3) << 3;
      gload_lds16(Bt + (size_t)(bn * 256 + row) * 1024 + kt + ko, Bs + c * 8);
    }
    // A: cvt prefetched regs -> LDS
    {
      bf16x8 o0, o1;
      o0[0] = (bf16_t)fA0.x; o0[1] = (bf16_t)fA0.y; o0[2] = (bf16_t)fA0.z; o0[3] = (bf16_t)fA0.w;
      o0[4] = (bf16_t)fA1.x; o0[5] = (bf16_t)fA1.y; o0[6] = (bf16_t)fA1.z; o0[7] = (bf16_t)fA1.w;
      o1[0] = (bf16_t)fA2.x; o1[1] = (bf16_t)fA2.y; o1[2] = (bf16_t)fA2.z; o1[3] = (bf16_t)fA2.w;
      o1[4] = (bf16_t)fA3.x; o1[5] = (bf16_t)fA3.y; o1[6] = (bf16_t)fA3.z; o1[7] = (bf16_t)fA3.w;
      *reinterpret_cast<bf16x8*>(As + arow * 32 + ako) = o0;
      *reinterpret_cast<bf16x8*>(As + arow * 32 + ako + 8) = o1;
    }
    if (kt + 32 < 1024) {
      const float* np = aptr + kt + 32;
      fA0 = *reinterpret_cast<const float4*>(np);
      fA1 = *reinterpret_cast<const float4*>(np + 4);
      fA2 = *reinterpret_cast<const float4*>(np + 8);
      fA3 = *reinterpret_cast<const float4*>(np + 12);
    }
    __syncthreads();
    bf16x8 af[4], bfr[8];
#pragma unroll
    for (int t = 0; t < 4; t++)
      af[t] = *reinterpret_cast<const bf16x8*>(As + (wm + t * 16 + lr) * 32 + g * 8);
#pragma unroll
    for (int t = 0; t < 8; t++)
      bfr[t] = *reinterpret_cast<const bf16x8*>(Bs + (wn + t * 16 + lr) * 32 + g * 8);
    __builtin_amdgcn_s_setprio(1);
#pragma unroll
    for (int i = 0; i < 4; i++)
#pragma unroll
      for (int j = 0; j < 8; j++)
        acc[i][j] = __builtin_amdgcn_mfma_f32_16x16x32_bf16(af[i], bfr[j], acc[i][j], 0, 0, 0);
    __builtin_amdgcn_s_setprio(0);
    __syncthreads();
  }

#pragma unroll
  for (int i = 0; i < 4; i++)
#pragma unroll
    for (int j = 0; j < 8; j++)
#pragma unroll
      for (int e = 0; e < 4; e++) {
        int row = (bm << 7) + wm + i * 16 + g * 4 + e;       // b*SEQ + s
        int col = (bnl << 8) + wn + j * 16 + lr;             // h*64 + d (0..1023)
        float v = acc[i][j][e];
        int b = row >> 11, s = row & 2047, h = col >> 6, d = col & 63;
        size_t bh32 = (size_t)((b << 4) + h) * 32;
        if (pn == 0) {
          qh[((size_t)(((b << 4) + h) * SEQ + s) << 6) + d] = (bf16_t)v;
        } else if (pn == 1) {
          int kt2 = s >> 6, u = s & 63, t32 = u >> 5, ql2 = u & 31;
          int kk2 = d >> 4, hq2 = (d >> 3) & 1, e2 = d & 7;
          Kf[(bh32 + kt2) * 4096 + (t32 * 4 + kk2) * 512 + (hq2 * 32 + ql2) * 8 + e2] = (bf16_t)v;
        } else {
          int kt2 = s >> 6, u = s & 63, s2 = u >> 4, hq2 = (u >> 3) & 1, e2 = u & 7;
          int dkt = d >> 5, ql2 = d & 31;
          Vf[(bh32 + kt2) * 4096 + (dkt * 4 + s2) * 512 + (hq2 * 32 + ql2) * 8 + e2] = (bf16_t)v;
        }
      }
}

// ---------- WO GEMM: [4096x1024] x [1024x1024]^T -> fp32, 64x128 tiles ----------
__global__ __launch_bounds__(256)
void k_gemm_wo(const bf16_t* __restrict__ A, const bf16_t* __restrict__ Bt,
               float* __restrict__ C) {
  __shared__ __align__(16) bf16_t As[64 * 32];
  __shared__ __align__(16) bf16_t Bs[128 * 32];
  const int tid = threadIdx.x;
  const int lane = tid & 63, wave = tid >> 6;
  const int g = lane >> 4, lr = lane & 15;
  const int bm = blockIdx.x, bn = blockIdx.y;
  const int wm = (wave >> 1) << 5, wn = (wave & 1) << 6;
  f32x4 acc[2][4] = {};

  for (int kt = 0; kt < 1024; kt += 32) {
    {
      int row = tid >> 2, ko = (tid & 3) << 3;
      gload_lds16(A + (size_t)(bm * 64 + row) * 1024 + kt + ko, As + tid * 8);
    }
#pragma unroll
    for (int cc = 0; cc < 2; cc++) {
      int c = tid + cc * 256;
      int row = c >> 2, ko = (c & 3) << 3;
      gload_lds16(Bt + (size_t)(bn * 128 + row) * 1024 + kt + ko, Bs + c * 8);
    }
    __syncthreads();
    bf16x8 af[2], bfr[4];
#pragma unroll
    for (int t = 0; t < 2; t++)
      af[t] = *reinterpret_cast<const bf16x8*>(As + (wm + t * 16 + lr) * 32 + g * 8);
#pragma unroll
    for (int t = 0; t < 4; t++)
      bfr[t] = *reinterpret_cast<const bf16x8*>(Bs + (wn + t * 16 + lr) * 32 + g * 8);
    __builtin_amdgcn_s_setprio(1);
#pragma unroll
    for (int i = 0; i < 2; i++)
#pragma unroll
      for (int j = 0; j < 4; j++)
        acc[i][j] = __builtin_amdgcn_mfma_f32_16x16x32_bf16(af[i], bfr[j], acc[i][j], 0, 0, 0);
    __builtin_amdgcn_s_setprio(0);
    __syncthreads();
  }
#pragma unroll
  for (int i = 0; i < 2; i++)
#pragma unroll
    for (int j = 0; j < 4; j++)
#pragma unroll
      for (int e = 0; e < 4; e++) {
        int row = (bm << 6) + wm + i * 16 + g * 4 + e;
        int col = (bn << 7) + wn + j * 16 + lr;
        C[(size_t)row * D_MODEL + col] = acc[i][j][e];
      }
}

// ---------- flash attention: exact R10-validated body (61 us) ----------
// 1D grid 512 blocks, 512 thr = 8 waves: wave w = (kvhalf hh = w>>2)*4 + qw.
// bid&7 = XCD; each XCD owns 4 bh x 16 q-tiles -> K/V hot set 2MB per L2.
__global__ __launch_bounds__(512, 4)
void k_attn6(const bf16_t* __restrict__ Qh, const bf16_t* __restrict__ Kf,
             const bf16_t* __restrict__ Vf, const bf16_t* __restrict__ Mf,
             bf16_t* __restrict__ O) {
  __shared__ __align__(16) bf16_t Ks[2][2][4096];   // [kvhalf][buf][8 frags x 64 lanes x 8]
  __shared__ __align__(16) bf16_t Vs[2][2][4096];
  const int bid = blockIdx.x;
  const int xcd = bid & 7, loc = bid >> 3;
  const int bh = xcd * 4 + (loc >> 4);      // 4 bh per XCD
  const int qtile = loc & 15;
  const int b = bh >> 4, h = bh & 15;
  const int tid = threadIdx.x, w = tid >> 6, lane = tid & 63;
  const int qw = w & 3, hh = w >> 2;
  const int hq = lane >> 5, ql = lane & 31;
  const int tid256 = tid & 255;
  const int qbase = qtile * 128 + qw * 32;
  const bf16_t* qp = Qh + (size_t)bh * SEQ * DKH;
  const bf16_t* kfp = Kf + (size_t)bh * 32 * 4096;
  const bf16_t* vfp = Vf + (size_t)bh * 32 * 4096;
  const int qt = qtile * 4 + qw;
  const bf16_t* mp = Mf + ((size_t)(qt * 32 + hh * 16) * 64 + lane) * 32;
  const int NIT = 16;

  bf16x8 aq[4];
#pragma unroll
  for (int kk = 0; kk < 4; kk++)
    aq[kk] = *reinterpret_cast<const bf16x8*>(
        qp + (size_t)(qbase + ql) * DKH + kk * 16 + hq * 8);

  f32x16 oacc[2] = {};
  float lsum = 0.f;

  auto stage = [&](int buf, int kt) {
#pragma unroll
    for (int cc = 0; cc < 2; cc++) {
      int c = tid256 + cc * 256;        // 512 16B-units per tile, fully linear
      gload_lds16(kfp + (size_t)kt * 4096 + c * 8, &Ks[hh][buf][c * 8]);
      gload_lds16(vfp + (size_t)kt * 4096 + c * 8, &Vs[hh][buf][c * 8]);
    }
  };

  stage(0, hh * 16);
  bf16x8 mv[4];
#pragma unroll
  for (int j = 0; j < 4; j++)
    mv[j] = *reinterpret_cast<const bf16x8*>(mp + j * 8);
  __syncthreads();

  for (int it = 0; it < NIT; ++it) {
    const int cur = it & 1;
    if (it + 1 < NIT) stage(cur ^ 1, hh * 16 + it + 1);

    const bf16_t* kb = Ks[hh][cur];
    const bf16_t* vb = Vs[hh][cur];

    // S^T = K Q^T : D[kv 32 rows][q = ql], rows = (reg&3)+8*(reg>>2)+4*hq
    f32x16 p[2];
#pragma unroll
    for (int t32 = 0; t32 < 2; t32++) {
      f32x16 a = {};
      __builtin_amdgcn_s_setprio(1);
#pragma unroll
      for (int kk = 0; kk < 4; kk++) {
        bf16x8 bk = *reinterpret_cast<const bf16x8*>(kb + (t32 * 4 + kk) * 512 + lane * 8);
        a = __builtin_amdgcn_mfma_f32_32x32x16_bf16(bk, aq[kk], a, 0, 0, 0);
      }
      __builtin_amdgcn_s_setprio(0);
      p[t32] = a;
    }

    // mask + exp2 -> pack to PV A-frags via permlane32_swap (validated R7)
    bf16x8 paf[4];
#pragma unroll
    for (int s = 0; s < 4; s++) {
      const int t32 = s >> 1, rb = (s & 1) * 8;
      float pes[8];
#pragma unroll
      for (int j = 0; j < 8; j++) {
        int v = t32 * 16 + rb + j;
        float x = p[t32][rb + j] + (float)mv[v >> 3][v & 7];
        float pe = fast_exp2(x);
        lsum += pe;
        pes[j] = pe;
      }
      uint32_t u0 = pkbf(pes[0], pes[1]), u1 = pkbf(pes[2], pes[3]);
      uint32_t w0 = pkbf(pes[4], pes[5]), w1 = pkbf(pes[6], pes[7]);
      perm32swap(u0, w0);          // low-kv word FIRST (vdst), high second
      perm32swap(u1, w1);
      union { uint32_t wd[4]; bf16x8 v8; } fu;
      fu.wd[0] = u0; fu.wd[1] = u1; fu.wd[2] = w0; fu.wd[3] = w1;
      paf[s] = fu.v8;
    }

    // prefetch next iter's mask (consumed after the barrier)
    {
      const bf16_t* mn = mp + (size_t)((it + 1 < NIT) ? (it + 1) : it) * 2048;
#pragma unroll
      for (int j = 0; j < 4; j++)
        mv[j] = *reinterpret_cast<const bf16x8*>(mn + j * 8);
    }

    // O += P V : A = paf (k-slot kv = 16s+8*hq+e), B = V frag (dkt*4+s)
#pragma unroll
    for (int dkt = 0; dkt < 2; dkt++) {
      __builtin_amdgcn_s_setprio(1);
#pragma unroll
      for (int s = 0; s < 4; s++) {
        bf16x8 bv = *reinterpret_cast<const bf16x8*>(vb + (dkt * 4 + s) * 512 + lane * 8);
        oacc[dkt] = __builtin_amdgcn_mfma_f32_32x32x16_bf16(paf[s], bv, oacc[dkt], 0, 0, 0);
      }
      __builtin_amdgcn_s_setprio(0);
    }
    __syncthreads();
  }

  // merge kv-halves via LDS (reuse Ks/Vs), then normalize + write (validated R8)
  float* smO = (float*)&Ks[0][0][0];   // 32 KB
  float* smL = (float*)&Vs[0][0][0];
  if (w >= 4) {
    int base = (qw * 64 + lane) * 32;
#pragma unroll
    for (int dkt = 0; dkt < 2; dkt++)
#pragma unroll
      for (int cg = 0; cg < 4; cg++) {
        int chs = ((dkt * 4 + cg) ^ (lane & 7)) * 4;
        float4 val = {oacc[dkt][cg * 4], oacc[dkt][cg * 4 + 1],
                      oacc[dkt][cg * 4 + 2], oacc[dkt][cg * 4 + 3]};
        *reinterpret_cast<float4*>(&smO[base + chs]) = val;
      }
    smL[qw * 64 + lane] = lsum;
  }
  __syncthreads();
  if (w < 4) {
    int base = (qw * 64 + lane) * 32;
#pragma unroll
    for (int dkt = 0; dkt < 2; dkt++)
#pragma unroll
      for (int cg = 0; cg < 4; cg++) {
        int chs = ((dkt * 4 + cg) ^ (lane & 7)) * 4;
        float4 pv = *reinterpret_cast<const float4*>(&smO[base + chs]);
#pragma unroll
        for (int e = 0; e < 4; e++) oacc[dkt][cg * 4 + e] += pv[e];
      }
    lsum += smL[qw * 64 + lane];
    float lf = lsum + __shfl_xor(lsum, 32);   // full row-sum for q = qbase+ql
    float inv[16];
#pragma unroll
    for (int reg = 0; reg < 16; reg++) {
      int qrow = (reg & 3) + 8 * (reg >> 2) + 4 * hq;
      inv[reg] = 1.0f / __shfl(lf, qrow);
    }
#pragma unroll
    for (int dkt = 0; dkt < 2; dkt++)
#pragma unroll
      for (int reg = 0; reg < 16; reg++) {
        int qrow = (reg & 3) + 8 * (reg >> 2) + 4 * hq;
        float v = oacc[dkt][reg] * inv[reg];
        O[(size_t)(b * SEQ + qbase + qrow) * D_MODEL + (h << 6) + dkt * 32 + ql] = (bf16_t)v;
      }
  }
}

extern "C" void kernel_launch(void* const* d_in, const int* in_sizes, int n_in,
                              void* d_out, int out_size, void* d_ws, size_t ws_size,
                              hipStream_t stream) {
  const float* Q  = (const float*)d_in[0];
  const float* K  = (const float*)d_in[1];
  const float* V  = (const float*)d_in[2];
  const float* M  = (const float*)d_in[3];
  const float* WQ = (const float*)d_in[5];
  const float* WK = (const float*)d_in[6];
  const float* WV = (const float*)d_in[7];
  const float* WO = (const float*)d_in[8];

  char* ws = (char*)d_ws;
  const size_t MB = 1 << 20;
  bf16_t* Mf    = (bf16_t*)(ws + 24 * MB);   // 8 MB bf16 fragment-order mask
  bf16_t* WqkvT = (bf16_t*)(ws + 32 * MB);   // 6 MB [3072][1024]
  bf16_t* WoT   = (bf16_t*)(ws + 38 * MB);   // 2 MB (contiguous after WqkvT)
  bf16_t* qh    = (bf16_t*)(ws + 40 * MB);   // [B,H,S,dk]
  bf16_t* Kf    = (bf16_t*)(ws + 48 * MB);   // 8 MB K fragment-order
  bf16_t* Vf    = (bf16_t*)(ws + 56 * MB);   // 8 MB V fragment-order
  bf16_t* Ob    = (bf16_t*)(ws + 64 * MB);   // [B,S,H*dk]

  k_maskg<<<4096, 256, 0, stream>>>(M, Mf);
  k_cvtw<<<16384, 256, 0, stream>>>(WQ, WK, WV, WO, WqkvT);

  k_gemm_qkv<<<dim3(32, 12), 256, 0, stream>>>(Q, K, V, WqkvT, qh, Kf, Vf);

  k_attn6<<<512, 512, 0, stream>>>(qh, Kf, Vf, Mf, Ob);

  k_gemm_wo<<<dim3(64, 8), 256, 0, stream>>>(Ob, WoT, (float*)d_out);
}

// Round 15
// 149.355 us; speedup vs baseline: 1.9966x; 1.0043x over previous
//
#include <hip/hip_runtime.h>
#include <hip/hip_bf16.h>
#include <stdint.h>

#define D_MODEL 1024
#define NHEAD 16
#define DKH 64
#define BATCH 2
#define SEQ 2048
#define LOG2E 1.44269504088896f

typedef __bf16 bf16_t;
typedef __bf16 bf16x8 __attribute__((ext_vector_type(8)));
typedef float f32x4 __attribute__((ext_vector_type(4)));
typedef float f32x16 __attribute__((ext_vector_type(16)));

__device__ __forceinline__ float fast_exp2(float x) {
#if __has_builtin(__builtin_amdgcn_exp2f)
  return __builtin_amdgcn_exp2f(x);
#else
  return exp2f(x);
#endif
}

// ---------- async global->LDS (16B per lane) ----------
__device__ __forceinline__ void gload_lds16(const bf16_t* g, bf16_t* l) {
  auto gp = (const __attribute__((address_space(1))) void*)(uintptr_t)g;
  auto lp = (__attribute__((address_space(3))) void*)(uintptr_t)l;
  __builtin_amdgcn_global_load_lds(gp, lp, 16, 0, 0);
}

// pack two f32 -> u32 of 2 bf16 (compiler emits v_cvt_pk_bf16_f32)
__device__ __forceinline__ uint32_t pkbf(float lo, float hi) {
  bf16_t a = (bf16_t)lo, c = (bf16_t)hi;
  uint16_t ua, uc;
  __builtin_memcpy(&ua, &a, 2);
  __builtin_memcpy(&uc, &c, 2);
  return (uint32_t)ua | ((uint32_t)uc << 16);
}

// v_permlane32_swap_b32 a, b: swaps a.lanes[32:63] <-> b.lanes[0:31]
// Call as perm32swap(low_kv_word, high_kv_word). (validated R7)
__device__ __forceinline__ void perm32swap(uint32_t& a, uint32_t& b) {
  asm volatile("v_permlane32_swap_b32 %0, %1" : "+v"(a), "+v"(b));
}

// Fused weight conversion.  n<3072: WqkvT[n][d] (Q scaled by 0.125*log2e);
// n>=3072: WoT[n-3072][d] = WO[d][n-3072].
__global__ void k_cvtw(const float* __restrict__ WQ, const float* __restrict__ WK,
                       const float* __restrict__ WV, const float* __restrict__ WO,
                       bf16_t* __restrict__ wt) {
  int j = blockIdx.x * 256 + threadIdx.x;        // 4M outputs
  int d = j & 1023, n = j >> 10;
  if (n < 3072) {
    int proj = n >> 10, h = (n >> 6) & 15, k = n & 63;
    const float* w = proj == 0 ? WQ : (proj == 1 ? WK : WV);
    float scale = proj == 0 ? (0.125f * LOG2E) : 1.0f;
    wt[j] = (bf16_t)(w[(h << 16) + (d << 6) + k] * scale);
  } else {
    wt[j] = (bf16_t)WO[(d << 10) + (n - 3072)];
  }
}

// Mask pre-gather for 32x32 swapped-QK D-layout, scaled by log2e, bf16 (validated R7/R10)
__global__ void k_maskg(const float* __restrict__ M, bf16_t* __restrict__ Mf) {
  int t = blockIdx.x * 256 + threadIdx.x;        // 1M threads, 4 vals each
  int wch = t & 7, lane = (t >> 3) & 63;
  int kvt = (t >> 9) & 31, qt = t >> 14;
  int h = lane >> 5, ql = lane & 31;
  int q = qt * 32 + ql;
  int t32 = wch >> 2, r2 = wch & 3;
  int kvb = kvt * 64 + t32 * 32 + 8 * r2 + 4 * h;
  float4 m4 = *reinterpret_cast<const float4*>(M + (size_t)q * SEQ + kvb);
  bf16_t o[4];
  o[0] = (bf16_t)(m4.x * LOG2E); o[1] = (bf16_t)(m4.y * LOG2E);
  o[2] = (bf16_t)(m4.z * LOG2E); o[3] = (bf16_t)(m4.w * LOG2E);
  *reinterpret_cast<ushort4*>(Mf + (size_t)t * 4) = *reinterpret_cast<ushort4*>(o);
}

// ---------- fused QKV projection GEMM, 128x128 tiles (R10 body) ----------
// 1D grid 768 blocks, XCD-clustered: xcd = bid&7 owns bm in [xcd*4, xcd*4+4)
// x all 24 bn -> per-XCD L2 hot set: 4 A-panels x 3 proj (6MB) + B panels.
// A fetched from L3 once per XCD instead of once per bn-tile.
__global__ __launch_bounds__(256)
void k_gemm_qkv(const float* __restrict__ Qs, const float* __restrict__ Ks32,
                const float* __restrict__ Vs32, const bf16_t* __restrict__ Bt,
                bf16_t* __restrict__ qh, bf16_t* __restrict__ Kf,
                bf16_t* __restrict__ Vf) {
  __shared__ __align__(16) bf16_t As[128 * 32];
  __shared__ __align__(16) bf16_t Bs[128 * 32];
  const int tid = threadIdx.x;
  const int lane = tid & 63, wave = tid >> 6;
  const int g = lane >> 4, lr = lane & 15;
  const int bid = blockIdx.x;
  const int xcd = bid & 7, jj = bid >> 3;     // jj in [0,96)
  const int bm = xcd * 4 + (jj & 3);          // [0,32)
  const int bn = jj >> 2;                     // [0,24)
  const int pn = bn >> 3;   // 0:q 1:k 2:v  (block-uniform)
  const float* Ap32 = pn == 0 ? Qs : (pn == 1 ? Ks32 : Vs32);
  const int wm = (wave >> 1) << 6, wn = (wave & 1) << 6;
  const int arow = tid >> 1, ako = (tid & 1) << 4;
  const float* aptr = Ap32 + (size_t)(bm * 128 + arow) * 1024 + ako;
  f32x4 acc[4][4] = {};

  float4 fA0 = *reinterpret_cast<const float4*>(aptr);
  float4 fA1 = *reinterpret_cast<const float4*>(aptr + 4);
  float4 fA2 = *reinterpret_cast<const float4*>(aptr + 8);
  float4 fA3 = *reinterpret_cast<const float4*>(aptr + 12);

  for (int kt = 0; kt < 1024; kt += 32) {
#pragma unroll
    for (int cc = 0; cc < 2; cc++) {
      int c = tid + cc * 256;
      int row = c >> 2, ko = (c & 3) << 3;
      gload_lds16(Bt + (size_t)(bn * 128 + row) * 1024 + kt + ko, Bs + c * 8);
    }
    {
      bf16x8 o0, o1;
      o0[0] = (bf16_t)fA0.x; o0[1] = (bf16_t)fA0.y; o0[2] = (bf16_t)fA0.z; o0[3] = (bf16_t)fA0.w;
      o0[4] = (bf16_t)fA1.x; o0[5] = (bf16_t)fA1.y; o0[6] = (bf16_t)fA1.z; o0[7] = (bf16_t)fA1.w;
      o1[0] = (bf16_t)fA2.x; o1[1] = (bf16_t)fA2.y; o1[2] = (bf16_t)fA2.z; o1[3] = (bf16_t)fA2.w;
      o1[4] = (bf16_t)fA3.x; o1[5] = (bf16_t)fA3.y; o1[6] = (bf16_t)fA3.z; o1[7] = (bf16_t)fA3.w;
      *reinterpret_cast<bf16x8*>(As + arow * 32 + ako) = o0;
      *reinterpret_cast<bf16x8*>(As + arow * 32 + ako + 8) = o1;
    }
    if (kt + 32 < 1024) {
      const float* np = aptr + kt + 32;
      fA0 = *reinterpret_cast<const float4*>(np);
      fA1 = *reinterpret_cast<const float4*>(np + 4);
      fA2 = *reinterpret_cast<const float4*>(np + 8);
      fA3 = *reinterpret_cast<const float4*>(np + 12);
    }
    __syncthreads();
    bf16x8 af[4], bfr[4];
#pragma unroll
    for (int t = 0; t < 4; t++)
      af[t] = *reinterpret_cast<const bf16x8*>(As + (wm + t * 16 + lr) * 32 + g * 8);
#pragma unroll
    for (int t = 0; t < 4; t++)
      bfr[t] = *reinterpret_cast<const bf16x8*>(Bs + (wn + t * 16 + lr) * 32 + g * 8);
    __builtin_amdgcn_s_setprio(1);
#pragma unroll
    for (int i = 0; i < 4; i++)
#pragma unroll
      for (int j = 0; j < 4; j++)
        acc[i][j] = __builtin_amdgcn_mfma_f32_16x16x32_bf16(af[i], bfr[j], acc[i][j], 0, 0, 0);
    __builtin_amdgcn_s_setprio(0);
    __syncthreads();
  }

#pragma unroll
  for (int i = 0; i < 4; i++)
#pragma unroll
    for (int j = 0; j < 4; j++)
#pragma unroll
      for (int e = 0; e < 4; e++) {
        int row = (bm << 7) + wm + i * 16 + g * 4 + e;       // b*SEQ + s
        int col = ((bn & 7) << 7) + wn + j * 16 + lr;        // h*64 + d
        float v = acc[i][j][e];
        int b = row >> 11, s = row & 2047, h = col >> 6, d = col & 63;
        size_t bh32 = (size_t)((b << 4) + h) * 32;
        if (pn == 0) {
          qh[((size_t)(((b << 4) + h) * SEQ + s) << 6) + d] = (bf16_t)v;
        } else if (pn == 1) {
          int kt2 = s >> 6, u = s & 63, t32 = u >> 5, ql2 = u & 31;
          int kk2 = d >> 4, hq2 = (d >> 3) & 1, e2 = d & 7;
          Kf[(bh32 + kt2) * 4096 + (t32 * 4 + kk2) * 512 + (hq2 * 32 + ql2) * 8 + e2] = (bf16_t)v;
        } else {
          int kt2 = s >> 6, u = s & 63, s2 = u >> 4, hq2 = (u >> 3) & 1, e2 = u & 7;
          int dkt = d >> 5, ql2 = d & 31;
          Vf[(bh32 + kt2) * 4096 + (dkt * 4 + s2) * 512 + (hq2 * 32 + ql2) * 8 + e2] = (bf16_t)v;
        }
      }
}

// ---------- WO GEMM: [4096x1024] x [1024x1024]^T -> fp32, 64x128 tiles ----------
// 1D grid 512, XCD-clustered: xcd owns 8 bm x all 8 bn -> hot set
// A 8x128KB + B 8x256KB = 3MB < 4MB L2.
__global__ __launch_bounds__(256)
void k_gemm_wo(const bf16_t* __restrict__ A, const bf16_t* __restrict__ Bt,
               float* __restrict__ C) {
  __shared__ __align__(16) bf16_t As[64 * 32];
  __shared__ __align__(16) bf16_t Bs[128 * 32];
  const int tid = threadIdx.x;
  const int lane = tid & 63, wave = tid >> 6;
  const int g = lane >> 4, lr = lane & 15;
  const int bid = blockIdx.x;
  const int xcd = bid & 7, jj = bid >> 3;     // jj in [0,64)
  const int bm = xcd * 8 + (jj & 7);          // [0,64)
  const int bn = jj >> 3;                     // [0,8)
  const int wm = (wave >> 1) << 5, wn = (wave & 1) << 6;
  f32x4 acc[2][4] = {};

  for (int kt = 0; kt < 1024; kt += 32) {
    {
      int row = tid >> 2, ko = (tid & 3) << 3;
      gload_lds16(A + (size_t)(bm * 64 + row) * 1024 + kt + ko, As + tid * 8);
    }
#pragma unroll
    for (int cc = 0; cc < 2; cc++) {
      int c = tid + cc * 256;
      int row = c >> 2, ko = (c & 3) << 3;
      gload_lds16(Bt + (size_t)(bn * 128 + row) * 1024 + kt + ko, Bs + c * 8);
    }
    __syncthreads();
    bf16x8 af[2], bfr[4];
#pragma unroll
    for (int t = 0; t < 2; t++)
      af[t] = *reinterpret_cast<const bf16x8*>(As + (wm + t * 16 + lr) * 32 + g * 8);
#pragma unroll
    for (int t = 0; t < 4; t++)
      bfr[t] = *reinterpret_cast<const bf16x8*>(Bs + (wn + t * 16 + lr) * 32 + g * 8);
    __builtin_amdgcn_s_setprio(1);
#pragma unroll
    for (int i = 0; i < 2; i++)
#pragma unroll
      for (int j = 0; j < 4; j++)
        acc[i][j] = __builtin_amdgcn_mfma_f32_16x16x32_bf16(af[i], bfr[j], acc[i][j], 0, 0, 0);
    __builtin_amdgcn_s_setprio(0);
    __syncthreads();
  }
#pragma unroll
  for (int i = 0; i < 2; i++)
#pragma unroll
    for (int j = 0; j < 4; j++)
#pragma unroll
      for (int e = 0; e < 4; e++) {
        int row = (bm << 6) + wm + i * 16 + g * 4 + e;
        int col = (bn << 7) + wn + j * 16 + lr;
        C[(size_t)row * D_MODEL + col] = acc[i][j][e];
      }
}

// ---------- flash attention: exact R10-validated body (61 us) ----------
// 1D grid 512 blocks, 512 thr = 8 waves: wave w = (kvhalf hh = w>>2)*4 + qw.
// bid&7 = XCD; each XCD owns 4 bh x 16 q-tiles -> K/V hot set 2MB per L2.
__global__ __launch_bounds__(512, 4)
void k_attn6(const bf16_t* __restrict__ Qh, const bf16_t* __restrict__ Kf,
             const bf16_t* __restrict__ Vf, const bf16_t* __restrict__ Mf,
             bf16_t* __restrict__ O) {
  __shared__ __align__(16) bf16_t Ks[2][2][4096];   // [kvhalf][buf][8 frags x 64 lanes x 8]
  __shared__ __align__(16) bf16_t Vs[2][2][4096];
  const int bid = blockIdx.x;
  const int xcd = bid & 7, loc = bid >> 3;
  const int bh = xcd * 4 + (loc >> 4);      // 4 bh per XCD
  const int qtile = loc & 15;
  const int b = bh >> 4, h = bh & 15;
  const int tid = threadIdx.x, w = tid >> 6, lane = tid & 63;
  const int qw = w & 3, hh = w >> 2;
  const int hq = lane >> 5, ql = lane & 31;
  const int tid256 = tid & 255;
  const int qbase = qtile * 128 + qw * 32;
  const bf16_t* qp = Qh + (size_t)bh * SEQ * DKH;
  const bf16_t* kfp = Kf + (size_t)bh * 32 * 4096;
  const bf16_t* vfp = Vf + (size_t)bh * 32 * 4096;
  const int qt = qtile * 4 + qw;
  const bf16_t* mp = Mf + ((size_t)(qt * 32 + hh * 16) * 64 + lane) * 32;
  const int NIT = 16;

  bf16x8 aq[4];
#pragma unroll
  for (int kk = 0; kk < 4; kk++)
    aq[kk] = *reinterpret_cast<const bf16x8*>(
        qp + (size_t)(qbase + ql) * DKH + kk * 16 + hq * 8);

  f32x16 oacc[2] = {};
  float lsum = 0.f;

  auto stage = [&](int buf, int kt) {
#pragma unroll
    for (int cc = 0; cc < 2; cc++) {
      int c = tid256 + cc * 256;        // 512 16B-units per tile, fully linear
      gload_lds16(kfp + (size_t)kt * 4096 + c * 8, &Ks[hh][buf][c * 8]);
      gload_lds16(vfp + (size_t)kt * 4096 + c * 8, &Vs[hh][buf][c * 8]);
    }
  };

  stage(0, hh * 16);
  bf16x8 mv[4];
#pragma unroll
  for (int j = 0; j < 4; j++)
    mv[j] = *reinterpret_cast<const bf16x8*>(mp + j * 8);
  __syncthreads();

  for (int it = 0; it < NIT; ++it) {
    const int cur = it & 1;
    if (it + 1 < NIT) stage(cur ^ 1, hh * 16 + it + 1);

    const bf16_t* kb = Ks[hh][cur];
    const bf16_t* vb = Vs[hh][cur];

    // S^T = K Q^T : D[kv 32 rows][q = ql], rows = (reg&3)+8*(reg>>2)+4*hq
    f32x16 p[2];
#pragma unroll
    for (int t32 = 0; t32 < 2; t32++) {
      f32x16 a = {};
      __builtin_amdgcn_s_setprio(1);
#pragma unroll
      for (int kk = 0; kk < 4; kk++) {
        bf16x8 bk = *reinterpret_cast<const bf16x8*>(kb + (t32 * 4 + kk) * 512 + lane * 8);
        a = __builtin_amdgcn_mfma_f32_32x32x16_bf16(bk, aq[kk], a, 0, 0, 0);
      }
      __builtin_amdgcn_s_setprio(0);
      p[t32] = a;
    }

    // mask + exp2 -> pack to PV A-frags via permlane32_swap (validated R7)
    bf16x8 paf[4];
#pragma unroll
    for (int s = 0; s < 4; s++) {
      const int t32 = s >> 1, rb = (s & 1) * 8;
      float pes[8];
#pragma unroll
      for (int j = 0; j < 8; j++) {
        int v = t32 * 16 + rb + j;
        float x = p[t32][rb + j] + (float)mv[v >> 3][v & 7];
        float pe = fast_exp2(x);
        lsum += pe;
        pes[j] = pe;
      }
      uint32_t u0 = pkbf(pes[0], pes[1]), u1 = pkbf(pes[2], pes[3]);
      uint32_t w0 = pkbf(pes[4], pes[5]), w1 = pkbf(pes[6], pes[7]);
      perm32swap(u0, w0);          // low-kv word FIRST (vdst), high second
      perm32swap(u1, w1);
      union { uint32_t wd[4]; bf16x8 v8; } fu;
      fu.wd[0] = u0; fu.wd[1] = u1; fu.wd[2] = w0; fu.wd[3] = w1;
      paf[s] = fu.v8;
    }

    // prefetch next iter's mask (consumed after the barrier)
    {
      const bf16_t* mn = mp + (size_t)((it + 1 < NIT) ? (it + 1) : it) * 2048;
#pragma unroll
      for (int j = 0; j < 4; j++)
        mv[j] = *reinterpret_cast<const bf16x8*>(mn + j * 8);
    }

    // O += P V : A = paf (k-slot kv = 16s+8*hq+e), B = V frag (dkt*4+s)
#pragma unroll
    for (int dkt = 0; dkt < 2; dkt++) {
      __builtin_amdgcn_s_setprio(1);
#pragma unroll
      for (int s = 0; s < 4; s++) {
        bf16x8 bv = *reinterpret_cast<const bf16x8*>(vb + (dkt * 4 + s) * 512 + lane * 8);
        oacc[dkt] = __builtin_amdgcn_mfma_f32_32x32x16_bf16(paf[s], bv, oacc[dkt], 0, 0, 0);
      }
      __builtin_amdgcn_s_setprio(0);
    }
    __syncthreads();
  }

  // merge kv-halves via LDS (reuse Ks/Vs), then normalize + write (validated R8)
  float* smO = (float*)&Ks[0][0][0];   // 32 KB
  float* smL = (float*)&Vs[0][0][0];
  if (w >= 4) {
    int base = (qw * 64 + lane) * 32;
#pragma unroll
    for (int dkt = 0; dkt < 2; dkt++)
#pragma unroll
      for (int cg = 0; cg < 4; cg++) {
        int chs = ((dkt * 4 + cg) ^ (lane & 7)) * 4;
        float4 val = {oacc[dkt][cg * 4], oacc[dkt][cg * 4 + 1],
                      oacc[dkt][cg * 4 + 2], oacc[dkt][cg * 4 + 3]};
        *reinterpret_cast<float4*>(&smO[base + chs]) = val;
      }
    smL[qw * 64 + lane] = lsum;
  }
  __syncthreads();
  if (w < 4) {
    int base = (qw * 64 + lane) * 32;
#pragma unroll
    for (int dkt = 0; dkt < 2; dkt++)
#pragma unroll
      for (int cg = 0; cg < 4; cg++) {
        int chs = ((dkt * 4 + cg) ^ (lane & 7)) * 4;
        float4 pv = *reinterpret_cast<const float4*>(&smO[base + chs]);
#pragma unroll
        for (int e = 0; e < 4; e++) oacc[dkt][cg * 4 + e] += pv[e];
      }
    lsum += smL[qw * 64 + lane];
    float lf = lsum + __shfl_xor(lsum, 32);   // full row-sum for q = qbase+ql
    float inv[16];
#pragma unroll
    for (int reg = 0; reg < 16; reg++) {
      int qrow = (reg & 3) + 8 * (reg >> 2) + 4 * hq;
      inv[reg] = 1.0f / __shfl(lf, qrow);
    }
#pragma unroll
    for (int dkt = 0; dkt < 2; dkt++)
#pragma unroll
      for (int reg = 0; reg < 16; reg++) {
        int qrow = (reg & 3) + 8 * (reg >> 2) + 4 * hq;
        float v = oacc[dkt][reg] * inv[reg];
        O[(size_t)(b * SEQ + qbase + qrow) * D_MODEL + (h << 6) + dkt * 32 + ql] = (bf16_t)v;
      }
  }
}

extern "C" void kernel_launch(void* const* d_in, const int* in_sizes, int n_in,
                              void* d_out, int out_size, void* d_ws, size_t ws_size,
                              hipStream_t stream) {
  const float* Q  = (const float*)d_in[0];
  const float* K  = (const float*)d_in[1];
  const float* V  = (const float*)d_in[2];
  const float* M  = (const float*)d_in[3];
  const float* WQ = (const float*)d_in[5];
  const float* WK = (const float*)d_in[6];
  const float* WV = (const float*)d_in[7];
  const float* WO = (const float*)d_in[8];

  char* ws = (char*)d_ws;
  const size_t MB = 1 << 20;
  bf16_t* Mf    = (bf16_t*)(ws + 24 * MB);   // 8 MB bf16 fragment-order mask
  bf16_t* WqkvT = (bf16_t*)(ws + 32 * MB);   // 6 MB [3072][1024]
  bf16_t* WoT   = (bf16_t*)(ws + 38 * MB);   // 2 MB (contiguous after WqkvT)
  bf16_t* qh    = (bf16_t*)(ws + 40 * MB);   // [B,H,S,dk]
  bf16_t* Kf    = (bf16_t*)(ws + 48 * MB);   // 8 MB K fragment-order
  bf16_t* Vf    = (bf16_t*)(ws + 56 * MB);   // 8 MB V fragment-order
  bf16_t* Ob    = (bf16_t*)(ws + 64 * MB);   // [B,S,H*dk]

  k_maskg<<<4096, 256, 0, stream>>>(M, Mf);
  k_cvtw<<<16384, 256, 0, stream>>>(WQ, WK, WV, WO, WqkvT);

  k_gemm_qkv<<<768, 256, 0, stream>>>(Q, K, V, WqkvT, qh, Kf, Vf);

  k_attn6<<<512, 512, 0, stream>>>(qh, Kf, Vf, Mf, Ob);

  k_gemm_wo<<<512, 256, 0, stream>>>(Ob, WoT, (float*)d_out);
}